// Round 12
// baseline (4566.862 us; speedup 1.0000x reference)
//
#include <hip/hip_runtime.h>

typedef unsigned short u16;
typedef unsigned long long u64;
typedef float f32x4 __attribute__((ext_vector_type(4)));
typedef short s16x8 __attribute__((ext_vector_type(8)));
typedef int i32x4 __attribute__((ext_vector_type(4)));

#define B_ 64
#define T_ 512
#define I_ 512
#define H_ 1024
#define NBLK 256
#define NTHR 256

// tagged-unit state buffers: unit = 16B = [4 x bf16 data | u32 tag | pad]
// s units:  [2 parity][4 bg][16 b][256 kq] x 16B   (kq = k/4)
// rs units: same layout
#define PAR_STRIDE 262144                 // 4*16*256*16
#define OFF_S   1024
#define OFF_RS  (OFF_S + 2 * PAR_STRIDE)
#define OFF_U   (OFF_RS + 2 * PAR_STRIDE) // bf16 U row-major [3][1024][1024] = 6291456
#define OFF_W   (OFF_U + 6291456)         // bf16 W row-major [3][1024][512]  = 3145728

__device__ __forceinline__ u16 f2bf(float f) {
  unsigned u = __float_as_uint(f);
  return (u16)((u + 0x7FFFu + ((u >> 16) & 1u)) >> 16);
}

__device__ __forceinline__ s16x8 pack8(float4 a, float4 b) {
  s16x8 r;
  r[0] = (short)f2bf(a.x); r[1] = (short)f2bf(a.y);
  r[2] = (short)f2bf(a.z); r[3] = (short)f2bf(a.w);
  r[4] = (short)f2bf(b.x); r[5] = (short)f2bf(b.y);
  r[6] = (short)f2bf(b.z); r[7] = (short)f2bf(b.w);
  return r;
}

// 16B device-coherent (MALL-direct) load/store; 16B single-transaction.
__device__ __forceinline__ void ld16v(i32x4* d, const char* p) {
  asm volatile("global_load_dwordx4 %0, %1, off sc0 sc1" : "=v"(*d) : "v"(p));
}
__device__ __forceinline__ void st16v(char* p, i32x4 v) {
  asm volatile("global_store_dwordx4 %0, %1, off sc0 sc1" :: "v"(p), "v"(v) : "memory");
}

__global__ void prep_kernel(const float* __restrict__ s0,
                            const float* __restrict__ Wz, const float* __restrict__ Wr,
                            const float* __restrict__ Ws, const float* __restrict__ Uz,
                            const float* __restrict__ Ur, const float* __restrict__ Us,
                            char* __restrict__ ws) {
  u16* ubf = (u16*)(ws + OFF_U);
  u16* wbf = (u16*)(ws + OFF_W);
  int tid = blockIdx.x * blockDim.x + threadIdx.x;
  int stride = gridDim.x * blockDim.x;
  const int NU = H_ * H_;
  for (int i = tid; i < NU; i += stride) {
    ubf[i] = f2bf(Uz[i]);
    ubf[NU + i] = f2bf(Ur[i]);
    ubf[2 * NU + i] = f2bf(Us[i]);
  }
  const int NW = H_ * I_;
  for (int i = tid; i < NW; i += stride) {
    wbf[i] = f2bf(Wz[i]);
    wbf[NW + i] = f2bf(Wr[i]);
    wbf[2 * NW + i] = f2bf(Ws[i]);
  }
  // s0 -> tagged units (parity 0, tag 0); wipe all other tags (replay safety)
  char* sb = ws + OFF_S;
  char* rb = ws + OFF_RS;
  for (int i = tid; i < 4 * 16 * 256; i += stride) {
    int bg = i >> 12, b = (i >> 8) & 15, kq = i & 255;
    const float* sp = s0 + (u64)(bg * 16 + b) * H_ + kq * 4;
    i32x4 u;
    u.x = (int)f2bf(sp[0]) | ((int)f2bf(sp[1]) << 16);
    u.y = (int)f2bf(sp[2]) | ((int)f2bf(sp[3]) << 16);
    u.z = 0; u.w = 0;                         // tag 0 = valid for t=0
    *(i32x4*)(sb + (u64)i * 16) = u;
    i32x4 z = {0, 0, -1, 0};                  // tag -1 = never valid
    *(i32x4*)(sb + PAR_STRIDE + (u64)i * 16) = z;
    *(i32x4*)(rb + (u64)i * 16) = z;
    *(i32x4*)(rb + PAR_STRIDE + (u64)i * 16) = z;
  }
}

#define SWZ(row, byteInRow, rowShift) \
  (((((row) << (rowShift)) + (byteInRow))) ^ (((row) & 7) << 4))

__global__ __launch_bounds__(NTHR, 1) void scan_kernel(
    const float* __restrict__ x, const float* __restrict__ mask,
    const float* __restrict__ bz, const float* __restrict__ br,
    const float* __restrict__ bs, const float* __restrict__ s0,
    char* __restrict__ ws, float* __restrict__ out) {

  __shared__ u16 u_lds[3 * 16 * 1024];   // 96KB U slices (swizzled, resident)
  __shared__ u16 w_lds[3 * 16 * 512];    // 48KB W slices (swizzled, resident)
  __shared__ f32x4 red1[4][2][64];       // 8KB  P1 cross-wave reduction
  __shared__ f32x4 red2[4][64];          // 4KB  P2 cross-wave reduction
  __shared__ u16 tbf[16][16];            // 512B wave-0 bf16 transpose tile
  __shared__ float tf32[16][16];         // 1KB  wave-0 f32 transpose tile

  char* sbuf = ws + OFF_S;
  char* rbuf = ws + OFF_RS;
  const u16* ubf = (const u16*)(ws + OFF_U);
  const u16* wbf = (const u16*)(ws + OFF_W);

  const int tid = threadIdx.x;
  const int jb = blockIdx.x;
  const int bg = jb & 3;          // batch group (16 batches)
  const int hs = jb >> 2;         // h-slice index (16 h columns)
  const int h0 = hs * 16;
  const int lane = tid & 63;
  const int wave = tid >> 6;
  const int ln15 = lane & 15;
  const int kg = lane >> 4;
  const int h = h0 + ln15;

  // one-time LDS preload of U and W slices for this h-slice
  for (int e = tid * 8; e < 3 * 16 * 1024; e += NTHR * 8) {
    int row = e >> 10, k = e & 1023;
    int g = row >> 4, hi = row & 15;
    uint4 v = *(const uint4*)(ubf + ((u64)(g * H_ + h0 + hi) * H_ + k));
    *(uint4*)((char*)u_lds + SWZ(row, (k << 1), 11)) = v;
  }
  for (int e = tid * 8; e < 3 * 16 * 512; e += NTHR * 8) {
    int row = e >> 9, k = e & 511;
    int g = row >> 4, hi = row & 15;
    uint4 v = *(const uint4*)(wbf + ((u64)(g * H_ + h0 + hi) * I_ + k));
    *(uint4*)((char*)w_lds + SWZ(row, (k << 1), 10)) = v;
  }
  const float bzv = bz[h];
  const float brv = br[h];
  const float bsv = bs[h];
  float sreg[4];   // wave 0 only: master f32 state for batches kg*4+j
  #pragma unroll
  for (int j = 0; j < 4; ++j)
    sreg[j] = s0[(u64)(bg * 16 + kg * 4 + j) * H_ + h];
  float mv[4];
  #pragma unroll
  for (int j = 0; j < 4; ++j) mv[j] = mask[(u64)(bg * 16 + kg * 4 + j) * T_];
  __syncthreads();

  // consumer per-lane unit offset: b=ln15, kq = wave*64 + q*8 + kg*2 + half
  const u64 laneoff = (u64)(bg * 4096 + ln15 * 256 + wave * 64 + kg * 2) * 16;
  // producer unit (wave0 lane): b=lane&15, kq = hs*4 + (lane>>4)
  const u64 prodoff = (u64)(bg * 4096 + (lane & 15) * 256 + hs * 4 + (lane >> 4)) * 16;

  // x A-frags + x-projection partials for step 0 (off the exchange path)
  s16x8 xf[4];
  #pragma unroll
  for (int i = 0; i < 4; ++i) {
    const float* xp = x + ((u64)(bg * 16 + ln15) * T_) * I_ + (wave * 4 + i) * 32 + kg * 8;
    xf[i] = pack8(*(const float4*)xp, *(const float4*)(xp + 4));
  }
  f32x4 axz = {0.f,0.f,0.f,0.f}, axr = {0.f,0.f,0.f,0.f}, axs = {0.f,0.f,0.f,0.f};
  #pragma unroll
  for (int i = 0; i < 4; ++i) {
    const int cb = (wave * 4 + i) * 64 + kg * 16;
    s16x8 w0 = *(const s16x8*)((const char*)w_lds + SWZ(ln15, cb, 10));
    s16x8 w1 = *(const s16x8*)((const char*)w_lds + SWZ(16 + ln15, cb, 10));
    s16x8 w2 = *(const s16x8*)((const char*)w_lds + SWZ(32 + ln15, cb, 10));
    axz = __builtin_amdgcn_mfma_f32_16x16x32_bf16(xf[i], w0, axz, 0, 0, 0);
    axr = __builtin_amdgcn_mfma_f32_16x16x32_bf16(xf[i], w1, axr, 0, 0, 0);
    axs = __builtin_amdgcn_mfma_f32_16x16x32_bf16(xf[i], w2, axs, 0, 0, 0);
  }
  float zv[4];

  for (int t = 0; t < T_; ++t) {
    const int par = t & 1;
    // ---------------- phase 1: z, r (poll tagged s units) ----------------
    i32x4 uu[16];
    {
      const char* sp1 = sbuf + (u64)par * PAR_STRIDE + laneoff;
      for (;;) {
        #pragma unroll
        for (int q = 0; q < 8; ++q) {
          ld16v(&uu[2 * q],     sp1 + q * 128);
          ld16v(&uu[2 * q + 1], sp1 + q * 128 + 16);
        }
        asm volatile("s_waitcnt vmcnt(0)" ::: "memory");
        __builtin_amdgcn_sched_barrier(0);
        int ok = 1;
        #pragma unroll
        for (int i = 0; i < 16; ++i) ok &= (uu[i].z == t);
        if (__all(ok)) break;
        __builtin_amdgcn_s_sleep(1);
      }
    }
    f32x4 accz = axz, accr = axr;
    #pragma unroll
    for (int q = 0; q < 8; ++q) {
      union { int w[4]; s16x8 v; } m;
      m.w[0] = uu[2 * q].x; m.w[1] = uu[2 * q].y;
      m.w[2] = uu[2 * q + 1].x; m.w[3] = uu[2 * q + 1].y;
      const int cb = (wave * 8 + q) * 64 + kg * 16;
      s16x8 b0 = *(const s16x8*)((const char*)u_lds + SWZ(ln15, cb, 11));
      s16x8 b1 = *(const s16x8*)((const char*)u_lds + SWZ(16 + ln15, cb, 11));
      accz = __builtin_amdgcn_mfma_f32_16x16x32_bf16(m.v, b0, accz, 0, 0, 0);
      accr = __builtin_amdgcn_mfma_f32_16x16x32_bf16(m.v, b1, accr, 0, 0, 0);
    }
    red1[wave][0][lane] = accz;
    red1[wave][1][lane] = accr;
    __syncthreads();
    if (wave == 0) {
      f32x4 az = red1[0][0][lane], ar = red1[0][1][lane];
      #pragma unroll
      for (int w = 1; w < 4; ++w) { az += red1[w][0][lane]; ar += red1[w][1][lane]; }
      #pragma unroll
      for (int j = 0; j < 4; ++j) {
        float z = 1.f / (1.f + __expf(-(az[j] + bzv)));
        float r = 1.f / (1.f + __expf(-(ar[j] + brv)));
        zv[j] = z;
        tbf[kg * 4 + j][ln15] = f2bf(sreg[j] * r);
      }
      // 64 self-signaling rs units (tag = t+1): data+tag in ONE 16B store
      uint2 d = *(const uint2*)&tbf[lane & 15][((lane >> 4)) * 4];
      i32x4 pk; pk.x = (int)d.x; pk.y = (int)d.y; pk.z = t + 1; pk.w = 0;
      st16v(rbuf + (u64)par * PAR_STRIDE + prodoff, pk);
    }

    // ---------------- phase 2: s_hat (poll tagged rs units) ----------------
    {
      const char* rp1 = rbuf + (u64)par * PAR_STRIDE + laneoff;
      for (;;) {
        #pragma unroll
        for (int q = 0; q < 8; ++q) {
          ld16v(&uu[2 * q],     rp1 + q * 128);
          ld16v(&uu[2 * q + 1], rp1 + q * 128 + 16);
        }
        asm volatile("s_waitcnt vmcnt(0)" ::: "memory");
        __builtin_amdgcn_sched_barrier(0);
        int ok = 1;
        #pragma unroll
        for (int i = 0; i < 16; ++i) ok &= (uu[i].z == t + 1);
        if (__all(ok)) break;
        __builtin_amdgcn_s_sleep(1);
      }
    }
    f32x4 accs = axs;
    #pragma unroll
    for (int q = 0; q < 8; ++q) {
      union { int w[4]; s16x8 v; } m;
      m.w[0] = uu[2 * q].x; m.w[1] = uu[2 * q].y;
      m.w[2] = uu[2 * q + 1].x; m.w[3] = uu[2 * q + 1].y;
      const int cb = (wave * 8 + q) * 64 + kg * 16;
      s16x8 b2 = *(const s16x8*)((const char*)u_lds + SWZ(32 + ln15, cb, 11));
      accs = __builtin_amdgcn_mfma_f32_16x16x32_bf16(m.v, b2, accs, 0, 0, 0);
    }
    red2[wave][lane] = accs;
    __syncthreads();
    if (wave == 0) {
      f32x4 as_ = red2[0][lane];
      #pragma unroll
      for (int w = 1; w < 4; ++w) as_ += red2[w][lane];
      #pragma unroll
      for (int j = 0; j < 4; ++j) {
        float shat = fmaxf(as_[j] + bsv, 0.f);
        float sn = (1.f - zv[j]) * sreg[j] + zv[j] * shat;
        float sf = sreg[j] + mv[j] * (sn - sreg[j]);
        sreg[j] = sf;
        tf32[kg * 4 + j][ln15] = sf;
        tbf[kg * 4 + j][ln15] = f2bf(sf);
      }
      // 64 self-signaling s units (tag = t+1, parity (t+1)&1)
      uint2 d = *(const uint2*)&tbf[lane & 15][((lane >> 4)) * 4];
      i32x4 pk; pk.x = (int)d.x; pk.y = (int)d.y; pk.z = t + 1; pk.w = 0;
      st16v(sbuf + (u64)((t + 1) & 1) * PAR_STRIDE + prodoff, pk);
      // out store (64B-coalesced), off the signal path by construction
      f32x4 o = *(const f32x4*)&tf32[lane >> 2][(lane & 3) * 4];
      f32x4* op = (f32x4*)(out + ((u64)(bg * 16 + (lane >> 2)) * T_ + t) * H_ + h0 + (lane & 3) * 4);
      __builtin_nontemporal_store(o, op);
    }
    // tail overlap: next step's x A-frags + 12 x-MFMAs + mask prefetch
    if (t + 1 < T_) {
      #pragma unroll
      for (int i = 0; i < 4; ++i) {
        const float* xp = x + ((u64)(bg * 16 + ln15) * T_ + (t + 1)) * I_ + (wave * 4 + i) * 32 + kg * 8;
        xf[i] = pack8(*(const float4*)xp, *(const float4*)(xp + 4));
      }
      axz = f32x4{0.f,0.f,0.f,0.f}; axr = f32x4{0.f,0.f,0.f,0.f}; axs = f32x4{0.f,0.f,0.f,0.f};
      #pragma unroll
      for (int i = 0; i < 4; ++i) {
        const int cb = (wave * 4 + i) * 64 + kg * 16;
        s16x8 w0 = *(const s16x8*)((const char*)w_lds + SWZ(ln15, cb, 10));
        s16x8 w1 = *(const s16x8*)((const char*)w_lds + SWZ(16 + ln15, cb, 10));
        s16x8 w2 = *(const s16x8*)((const char*)w_lds + SWZ(32 + ln15, cb, 10));
        axz = __builtin_amdgcn_mfma_f32_16x16x32_bf16(xf[i], w0, axz, 0, 0, 0);
        axr = __builtin_amdgcn_mfma_f32_16x16x32_bf16(xf[i], w1, axr, 0, 0, 0);
        axs = __builtin_amdgcn_mfma_f32_16x16x32_bf16(xf[i], w2, axs, 0, 0, 0);
      }
      if (wave == 0) {
        #pragma unroll
        for (int j = 0; j < 4; ++j) mv[j] = mask[(u64)(bg * 16 + kg * 4 + j) * T_ + (t + 1)];
      }
    }
  }
}

extern "C" void kernel_launch(void* const* d_in, const int* in_sizes, int n_in,
                              void* d_out, int out_size, void* d_ws, size_t ws_size,
                              hipStream_t stream) {
  const float* x   = (const float*)d_in[0];
  const float* msk = (const float*)d_in[1];
  const float* s0  = (const float*)d_in[2];
  const float* Ws_ = (const float*)d_in[3];
  const float* Wr_ = (const float*)d_in[4];
  const float* Wz_ = (const float*)d_in[5];
  const float* Us_ = (const float*)d_in[6];
  const float* Ur_ = (const float*)d_in[7];
  const float* Uz_ = (const float*)d_in[8];
  const float* bs_ = (const float*)d_in[9];
  const float* br_ = (const float*)d_in[10];
  const float* bz_ = (const float*)d_in[11];
  float* out = (float*)d_out;
  char* ws = (char*)d_ws;

  hipLaunchKernelGGL(prep_kernel, dim3(1024), dim3(256), 0, stream,
                     s0, Wz_, Wr_, Ws_, Uz_, Ur_, Us_, ws);
  hipLaunchKernelGGL(scan_kernel, dim3(NBLK), dim3(NTHR), 0, stream,
                     x, msk, bz_, br_, bs_, s0, ws, out);
}

// Round 13
// 2660.541 us; speedup vs baseline: 1.7165x; 1.7165x over previous
//
#include <hip/hip_runtime.h>

typedef unsigned short u16;
typedef unsigned long long u64;
typedef float f32x4 __attribute__((ext_vector_type(4)));
typedef short s16x8 __attribute__((ext_vector_type(8)));

#define B_ 64
#define T_ 512
#define I_ 512
#define H_ 1024
#define NBLK 256
#define NGRP 4      // batch groups (16 batches each), independent domains
#define NMEM 64     // blocks (h-slices) per group
#define NTHR 256

// workspace layout (bytes)
#define OFF_FLG 0                        // [4 bg][64 hs] x 128B = 32768
#define OFF_SBF 32768                    // s bf16 frags [4 bg][32 kc][64 lane]x16B = 131072
#define OFF_RS  (OFF_SBF + 131072)      // r*s bf16 frags, same layout = 131072
#define OFF_U   (OFF_RS + 131072)       // bf16 U row-major [3][1024][1024] = 6291456
#define OFF_W   (OFF_U + 6291456)       // bf16 W row-major [3][1024][512]  = 3145728

__device__ __forceinline__ u16 f2bf(float f) {
  unsigned u = __float_as_uint(f);
  return (u16)((u + 0x7FFFu + ((u >> 16) & 1u)) >> 16);
}

__device__ __forceinline__ s16x8 pack8(float4 a, float4 b) {
  s16x8 r;
  r[0] = (short)f2bf(a.x); r[1] = (short)f2bf(a.y);
  r[2] = (short)f2bf(a.z); r[3] = (short)f2bf(a.w);
  r[4] = (short)f2bf(b.x); r[5] = (short)f2bf(b.y);
  r[6] = (short)f2bf(b.z); r[7] = (short)f2bf(b.w);
  return r;
}

// 16B device-coherent (MALL-direct) load/store. Load returns before data
// arrives — caller MUST s_waitcnt vmcnt(0) + sched_barrier(0) before use.
__device__ __forceinline__ void ld16_sc1(s16x8* d, const char* p) {
  asm volatile("global_load_dwordx4 %0, %1, off sc0 sc1" : "=v"(*d) : "v"(p));
}
__device__ __forceinline__ void st16_sc1(char* p, s16x8 v) {
  asm volatile("global_store_dwordx4 %0, %1, off sc0 sc1" :: "v"(p), "v"(v) : "memory");
}

__global__ void prep_kernel(const float* __restrict__ s0,
                            const float* __restrict__ Wz, const float* __restrict__ Wr,
                            const float* __restrict__ Ws, const float* __restrict__ Uz,
                            const float* __restrict__ Ur, const float* __restrict__ Us,
                            char* __restrict__ ws) {
  u16* ubf = (u16*)(ws + OFF_U);
  u16* wbf = (u16*)(ws + OFF_W);
  int tid = blockIdx.x * blockDim.x + threadIdx.x;
  int stride = gridDim.x * blockDim.x;
  const int NU = H_ * H_;
  for (int i = tid; i < NU; i += stride) {
    ubf[i] = f2bf(Uz[i]);
    ubf[NU + i] = f2bf(Ur[i]);
    ubf[2 * NU + i] = f2bf(Us[i]);
  }
  const int NW = H_ * I_;
  for (int i = tid; i < NW; i += stride) {
    wbf[i] = f2bf(Wz[i]);
    wbf[NW + i] = f2bf(Wr[i]);
    wbf[2 * NW + i] = f2bf(Ws[i]);
  }
  // s0 -> frag-layout bf16: [bg][kc][lane]; b = bg*16 + (l&15), k = kc*32 + (l>>4)*8
  for (int f = tid; f < 4 * 32 * 64; f += stride) {
    int kc = (f >> 6) & 31, l = f & 63;
    int b = (f >> 11) * 16 + (l & 15);
    int k = kc * 32 + (l >> 4) * 8;
    const float* sp = s0 + (u64)b * H_ + k;
    ushort4 lo, hi;
    lo.x = f2bf(sp[0]); lo.y = f2bf(sp[1]); lo.z = f2bf(sp[2]); lo.w = f2bf(sp[3]);
    hi.x = f2bf(sp[4]); hi.y = f2bf(sp[5]); hi.z = f2bf(sp[6]); hi.w = f2bf(sp[7]);
    ushort4* dst = (ushort4*)(ws + OFF_SBF + (u64)f * 16);
    dst[0] = lo; dst[1] = hi;
  }
}

// R8/R10-proven poll: ONLY threads 0-63 poll (lane l -> producer l's own 128B
// line), then __syncthreads broadcasts. Single flag per block per phase.
__device__ __forceinline__ void bar_poll(const unsigned* flags, int bg, unsigned bidx) {
  if (threadIdx.x < NMEM) {
    while (__hip_atomic_load(flags + (u64)(bg * NMEM + threadIdx.x) * 32,
                             __ATOMIC_RELAXED, __HIP_MEMORY_SCOPE_AGENT) < bidx)
      __builtin_amdgcn_s_sleep(1);
  }
  __syncthreads();
}

#define SWZ(row, byteInRow, rowShift) \
  (((((row) << (rowShift)) + (byteInRow))) ^ (((row) & 7) << 4))

__global__ __launch_bounds__(NTHR, 1) void scan_kernel(
    const float* __restrict__ x, const float* __restrict__ mask,
    const float* __restrict__ bz, const float* __restrict__ br,
    const float* __restrict__ bs, const float* __restrict__ s0,
    char* __restrict__ ws, float* __restrict__ out) {

  __shared__ u16 u_lds[3 * 16 * 1024];   // 96KB U slices (swizzled, resident)
  __shared__ u16 w_lds[3 * 16 * 512];    // 48KB W slices (swizzled, resident)
  __shared__ f32x4 red1[4][2][64];       // 8KB  P1 cross-wave reduction
  __shared__ f32x4 red2[4][64];          // 4KB  P2 cross-wave reduction
  __shared__ u16 tbw[4][4][16];          // 512B per-wave transpose tiles

  char* fsb = ws + OFF_SBF;
  char* frb = ws + OFF_RS;
  const u16* ubf = (const u16*)(ws + OFF_U);
  const u16* wbf = (const u16*)(ws + OFF_W);
  unsigned* flags = (unsigned*)(ws + OFF_FLG);

  const int tid = threadIdx.x;
  const int jb = blockIdx.x;
  const int bg = jb & 3;          // batch group (16 batches)
  const int hs = jb >> 2;         // h-slice index (16 h columns)
  const int h0 = hs * 16;
  const int lane = tid & 63;
  const int wave = tid >> 6;
  const int ln15 = lane & 15;
  const int kg = lane >> 4;
  const int h = h0 + ln15;
  const int Bl = 4 * wave + kg;   // this lane's epilogue batch (wave owns [4w,4w+4))

  // one-time LDS preload of U and W slices for this h-slice
  for (int e = tid * 8; e < 3 * 16 * 1024; e += NTHR * 8) {
    int row = e >> 10, k = e & 1023;
    int g = row >> 4, hi = row & 15;
    uint4 v = *(const uint4*)(ubf + ((u64)(g * H_ + h0 + hi) * H_ + k));
    *(uint4*)((char*)u_lds + SWZ(row, (k << 1), 11)) = v;
  }
  for (int e = tid * 8; e < 3 * 16 * 512; e += NTHR * 8) {
    int row = e >> 9, k = e & 511;
    int g = row >> 4, hi = row & 15;
    uint4 v = *(const uint4*)(wbf + ((u64)(g * H_ + h0 + hi) * I_ + k));
    *(uint4*)((char*)w_lds + SWZ(row, (k << 1), 10)) = v;
  }
  const float bzv = bz[h];
  const float brv = br[h];
  const float bsv = bs[h];
  float sreg = s0[(u64)(bg * 16 + Bl) * H_ + h];   // 1 master state value/lane
  float mv = mask[(u64)(bg * 16 + Bl) * T_];       // mask for t=0
  __syncthreads();

  // consumer load bases (wave's kc range = wave*8 .. +8)
  const char* sbase = fsb + (((u64)bg * 32 + wave * 8) * 64 + lane) * 16;
  const char* rbase = frb + (((u64)bg * 32 + wave * 8) * 64 + lane) * 16;
  // producer chunk dst (active lanes l<8 per wave): batch 4w+(l&3), h-half l>>2
  const int lp = (4 * wave + (lane & 3)) + 16 * ((hs & 1) * 2 + ((lane >> 2) & 1));
  char* sdst = fsb + (((u64)bg * 32 + (hs >> 1)) * 64 + lp) * 16;
  char* rdst = frb + (((u64)bg * 32 + (hs >> 1)) * 64 + lp) * 16;
  unsigned* blockflag = flags + (u64)(bg * NMEM + hs) * 32;

  // x A-frags + x-projection partials for step 0 (off the exchange path)
  s16x8 xf[4];
  #pragma unroll
  for (int i = 0; i < 4; ++i) {
    const float* xp = x + ((u64)(bg * 16 + ln15) * T_) * I_ + (wave * 4 + i) * 32 + kg * 8;
    xf[i] = pack8(*(const float4*)xp, *(const float4*)(xp + 4));
  }
  f32x4 axz = {0.f,0.f,0.f,0.f}, axr = {0.f,0.f,0.f,0.f}, axs = {0.f,0.f,0.f,0.f};
  #pragma unroll
  for (int i = 0; i < 4; ++i) {
    const int cb = (wave * 4 + i) * 64 + kg * 16;
    s16x8 w0 = *(const s16x8*)((const char*)w_lds + SWZ(ln15, cb, 10));
    s16x8 w1 = *(const s16x8*)((const char*)w_lds + SWZ(16 + ln15, cb, 10));
    s16x8 w2 = *(const s16x8*)((const char*)w_lds + SWZ(32 + ln15, cb, 10));
    axz = __builtin_amdgcn_mfma_f32_16x16x32_bf16(xf[i], w0, axz, 0, 0, 0);
    axr = __builtin_amdgcn_mfma_f32_16x16x32_bf16(xf[i], w1, axr, 0, 0, 0);
    axs = __builtin_amdgcn_mfma_f32_16x16x32_bf16(xf[i], w2, axs, 0, 0, 0);
  }
  unsigned bidx = 0;
  float zval = 0.f;

  for (int t = 0; t < T_; ++t) {
    // ---------------- phase 1: z, r ----------------
    s16x8 aS[8];
    #pragma unroll
    for (int q = 0; q < 8; ++q) ld16_sc1(&aS[q], sbase + q * 1024);
    __builtin_amdgcn_sched_barrier(0);
    asm volatile("s_waitcnt vmcnt(0)" ::: "memory");
    __builtin_amdgcn_sched_barrier(0);
    f32x4 accz = axz, accr = axr;
    #pragma unroll
    for (int q = 0; q < 8; ++q) {
      const int cb = (wave * 8 + q) * 64 + kg * 16;
      s16x8 b0 = *(const s16x8*)((const char*)u_lds + SWZ(ln15, cb, 11));
      s16x8 b1 = *(const s16x8*)((const char*)u_lds + SWZ(16 + ln15, cb, 11));
      accz = __builtin_amdgcn_mfma_f32_16x16x32_bf16(aS[q], b0, accz, 0, 0, 0);
      accr = __builtin_amdgcn_mfma_f32_16x16x32_bf16(aS[q], b1, accr, 0, 0, 0);
    }
    red1[wave][0][lane] = accz;
    red1[wave][1][lane] = accr;
    __syncthreads();
    ++bidx;
    {  // distributed epilogue: lane -> (batch Bl, col h)
      float az = 0.f, ar = 0.f;
      #pragma unroll
      for (int w2 = 0; w2 < 4; ++w2) {
        const float* pz = (const float*)&red1[w2][0][wave * 16 + ln15];
        const float* pr = (const float*)&red1[w2][1][wave * 16 + ln15];
        az += pz[kg];
        ar += pr[kg];
      }
      float z = 1.f / (1.f + __expf(-(az + bzv)));
      float r = 1.f / (1.f + __expf(-(ar + brv)));
      zval = z;
      tbw[wave][kg][ln15] = f2bf(sreg * r);     // wave-private transpose tile
      if (lane < 8) {
        s16x8 v = *(const s16x8*)&tbw[wave][lane & 3][((lane >> 2) & 1) * 8];
        st16_sc1(rdst, v);
      }
      asm volatile("s_waitcnt vmcnt(0)" ::: "memory");  // per-wave drain
    }
    __syncthreads();   // all waves' rs stores drained
    if (tid == 0)
      __hip_atomic_store(blockflag, bidx, __ATOMIC_RELAXED, __HIP_MEMORY_SCOPE_AGENT);
    bar_poll(flags, bg, bidx);

    // ---------------- phase 2: s_hat, state update ----------------
    s16x8 aR[8];
    #pragma unroll
    for (int q = 0; q < 8; ++q) ld16_sc1(&aR[q], rbase + q * 1024);
    __builtin_amdgcn_sched_barrier(0);
    asm volatile("s_waitcnt vmcnt(0)" ::: "memory");
    __builtin_amdgcn_sched_barrier(0);
    f32x4 accs = axs;
    #pragma unroll
    for (int q = 0; q < 8; ++q) {
      const int cb = (wave * 8 + q) * 64 + kg * 16;
      s16x8 b2 = *(const s16x8*)((const char*)u_lds + SWZ(32 + ln15, cb, 11));
      accs = __builtin_amdgcn_mfma_f32_16x16x32_bf16(aR[q], b2, accs, 0, 0, 0);
    }
    red2[wave][lane] = accs;
    __syncthreads();
    ++bidx;
    float sf;
    {
      float as_ = 0.f;
      #pragma unroll
      for (int w2 = 0; w2 < 4; ++w2) {
        const float* ps = (const float*)&red2[w2][wave * 16 + ln15];
        as_ += ps[kg];
      }
      float shat = fmaxf(as_ + bsv, 0.f);
      float sn = (1.f - zval) * sreg + zval * shat;
      sf = sreg + mv * (sn - sreg);
      sreg = sf;
      tbw[wave][kg][ln15] = f2bf(sf);
      if (lane < 8) {
        s16x8 v = *(const s16x8*)&tbw[wave][lane & 3][((lane >> 2) & 1) * 8];
        st16_sc1(sdst, v);
      }
      asm volatile("s_waitcnt vmcnt(0)" ::: "memory");  // per-wave drain
    }
    __syncthreads();   // all waves' s stores drained
    if (tid == 0)
      __hip_atomic_store(blockflag, bidx, __ATOMIC_RELAXED, __HIP_MEMORY_SCOPE_AGENT);
    // out store after signal (64B-coalesced per batch row), off the drain path
    __builtin_nontemporal_store(sf, out + ((u64)(bg * 16 + Bl) * T_ + t) * H_ + h);
    // tail overlap: next step's x frags + 12 x-MFMAs + mask prefetch
    if (t + 1 < T_) {
      #pragma unroll
      for (int i = 0; i < 4; ++i) {
        const float* xp = x + ((u64)(bg * 16 + ln15) * T_ + (t + 1)) * I_ + (wave * 4 + i) * 32 + kg * 8;
        xf[i] = pack8(*(const float4*)xp, *(const float4*)(xp + 4));
      }
      axz = f32x4{0.f,0.f,0.f,0.f}; axr = f32x4{0.f,0.f,0.f,0.f}; axs = f32x4{0.f,0.f,0.f,0.f};
      #pragma unroll
      for (int i = 0; i < 4; ++i) {
        const int cb = (wave * 4 + i) * 64 + kg * 16;
        s16x8 w0 = *(const s16x8*)((const char*)w_lds + SWZ(ln15, cb, 10));
        s16x8 w1 = *(const s16x8*)((const char*)w_lds + SWZ(16 + ln15, cb, 10));
        s16x8 w2 = *(const s16x8*)((const char*)w_lds + SWZ(32 + ln15, cb, 10));
        axz = __builtin_amdgcn_mfma_f32_16x16x32_bf16(xf[i], w0, axz, 0, 0, 0);
        axr = __builtin_amdgcn_mfma_f32_16x16x32_bf16(xf[i], w1, axr, 0, 0, 0);
        axs = __builtin_amdgcn_mfma_f32_16x16x32_bf16(xf[i], w2, axs, 0, 0, 0);
      }
      mv = mask[(u64)(bg * 16 + Bl) * T_ + (t + 1)];
    }
    bar_poll(flags, bg, bidx);
  }
}

extern "C" void kernel_launch(void* const* d_in, const int* in_sizes, int n_in,
                              void* d_out, int out_size, void* d_ws, size_t ws_size,
                              hipStream_t stream) {
  const float* x   = (const float*)d_in[0];
  const float* msk = (const float*)d_in[1];
  const float* s0  = (const float*)d_in[2];
  const float* Ws_ = (const float*)d_in[3];
  const float* Wr_ = (const float*)d_in[4];
  const float* Wz_ = (const float*)d_in[5];
  const float* Us_ = (const float*)d_in[6];
  const float* Ur_ = (const float*)d_in[7];
  const float* Uz_ = (const float*)d_in[8];
  const float* bs_ = (const float*)d_in[9];
  const float* br_ = (const float*)d_in[10];
  const float* bz_ = (const float*)d_in[11];
  float* out = (float*)d_out;
  char* ws = (char*)d_ws;

  (void)hipMemsetAsync(d_ws, 0, 32768, stream);  // per-block flags (128B spread)
  hipLaunchKernelGGL(prep_kernel, dim3(1024), dim3(256), 0, stream,
                     s0, Wz_, Wr_, Ws_, Uz_, Ur_, Us_, ws);
  hipLaunchKernelGGL(scan_kernel, dim3(NBLK), dim3(NTHR), 0, stream,
                     x, msk, bz_, br_, bs_, s0, ws, out);
}

// Round 14
// 2520.626 us; speedup vs baseline: 1.8118x; 1.0555x over previous
//
#include <hip/hip_runtime.h>

typedef unsigned short u16;
typedef unsigned long long u64;
typedef float f32x4 __attribute__((ext_vector_type(4)));
typedef short s16x8 __attribute__((ext_vector_type(8)));

#define B_ 64
#define T_ 512
#define I_ 512
#define H_ 1024
#define NBLK 256
#define NGRP 4      // batch groups (16 batches each), independent domains
#define NMEM 64     // blocks (h-slices) per group
#define NTHR 256

// workspace layout (bytes)
#define OFF_FLG 0                        // [4 bg][64 hs] x 128B = 32768
#define OFF_SBF 32768                    // s bf16 frags [4 bg][32 kc][64 lane]x16B = 131072
#define OFF_RS  (OFF_SBF + 131072)      // r*s bf16 frags, same layout = 131072
#define OFF_U   (OFF_RS + 131072)       // bf16 U row-major [3][1024][1024] = 6291456
#define OFF_W   (OFF_U + 6291456)       // bf16 W row-major [3][1024][512]  = 3145728

__device__ __forceinline__ u16 f2bf(float f) {
  unsigned u = __float_as_uint(f);
  return (u16)((u + 0x7FFFu + ((u >> 16) & 1u)) >> 16);
}

__device__ __forceinline__ s16x8 pack8(float4 a, float4 b) {
  s16x8 r;
  r[0] = (short)f2bf(a.x); r[1] = (short)f2bf(a.y);
  r[2] = (short)f2bf(a.z); r[3] = (short)f2bf(a.w);
  r[4] = (short)f2bf(b.x); r[5] = (short)f2bf(b.y);
  r[6] = (short)f2bf(b.z); r[7] = (short)f2bf(b.w);
  return r;
}

// 16B device-coherent (MALL-direct) load/store. Load returns before data
// arrives — caller MUST s_waitcnt vmcnt(0) + sched_barrier(0) before use.
__device__ __forceinline__ void ld16_sc1(s16x8* d, const char* p) {
  asm volatile("global_load_dwordx4 %0, %1, off sc0 sc1" : "=v"(*d) : "v"(p));
}
__device__ __forceinline__ void st16_sc1(char* p, s16x8 v) {
  asm volatile("global_store_dwordx4 %0, %1, off sc0 sc1" :: "v"(p), "v"(v) : "memory");
}

__global__ void prep_kernel(const float* __restrict__ s0,
                            const float* __restrict__ Wz, const float* __restrict__ Wr,
                            const float* __restrict__ Ws, const float* __restrict__ Uz,
                            const float* __restrict__ Ur, const float* __restrict__ Us,
                            char* __restrict__ ws) {
  u16* ubf = (u16*)(ws + OFF_U);
  u16* wbf = (u16*)(ws + OFF_W);
  int tid = blockIdx.x * blockDim.x + threadIdx.x;
  int stride = gridDim.x * blockDim.x;
  const int NU = H_ * H_;
  for (int i = tid; i < NU; i += stride) {
    ubf[i] = f2bf(Uz[i]);
    ubf[NU + i] = f2bf(Ur[i]);
    ubf[2 * NU + i] = f2bf(Us[i]);
  }
  const int NW = H_ * I_;
  for (int i = tid; i < NW; i += stride) {
    wbf[i] = f2bf(Wz[i]);
    wbf[NW + i] = f2bf(Wr[i]);
    wbf[2 * NW + i] = f2bf(Ws[i]);
  }
  // s0 -> frag-layout bf16: [bg][kc][lane]; b = bg*16 + (l&15), k = kc*32 + (l>>4)*8
  for (int f = tid; f < 4 * 32 * 64; f += stride) {
    int kc = (f >> 6) & 31, l = f & 63;
    int b = (f >> 11) * 16 + (l & 15);
    int k = kc * 32 + (l >> 4) * 8;
    const float* sp = s0 + (u64)b * H_ + k;
    ushort4 lo, hi;
    lo.x = f2bf(sp[0]); lo.y = f2bf(sp[1]); lo.z = f2bf(sp[2]); lo.w = f2bf(sp[3]);
    hi.x = f2bf(sp[4]); hi.y = f2bf(sp[5]); hi.z = f2bf(sp[6]); hi.w = f2bf(sp[7]);
    ushort4* dst = (ushort4*)(ws + OFF_SBF + (u64)f * 16);
    dst[0] = lo; dst[1] = hi;
  }
}

// R8/R10-proven poll: ONLY threads 0-63 poll (lane l -> producer l's own 128B
// line), then __syncthreads broadcasts. Single flag per block per phase.
__device__ __forceinline__ void bar_poll(const unsigned* flags, int bg, unsigned bidx) {
  if (threadIdx.x < NMEM) {
    while (__hip_atomic_load(flags + (u64)(bg * NMEM + threadIdx.x) * 32,
                             __ATOMIC_RELAXED, __HIP_MEMORY_SCOPE_AGENT) < bidx)
      __builtin_amdgcn_s_sleep(1);
  }
  __syncthreads();
}

#define SWZ(row, byteInRow, rowShift) \
  (((((row) << (rowShift)) + (byteInRow))) ^ (((row) & 7) << 4))

__global__ __launch_bounds__(NTHR, 1) void scan_kernel(
    const float* __restrict__ x, const float* __restrict__ mask,
    const float* __restrict__ bz, const float* __restrict__ br,
    const float* __restrict__ bs, const float* __restrict__ s0,
    char* __restrict__ ws, float* __restrict__ out) {

  __shared__ u16 u_lds[3 * 16 * 1024];   // 96KB U slices (prologue staging only)
  __shared__ u16 w_lds[3 * 16 * 512];    // 48KB W slices (prologue staging only)
  __shared__ f32x4 red1[4][2][64];       // 8KB  P1 cross-wave reduction
  __shared__ f32x4 red2[4][64];          // 4KB  P2 cross-wave reduction
  __shared__ u16 tbw[4][4][16];          // 512B per-wave transpose tiles

  char* fsb = ws + OFF_SBF;
  char* frb = ws + OFF_RS;
  const u16* ubf = (const u16*)(ws + OFF_U);
  const u16* wbf = (const u16*)(ws + OFF_W);
  unsigned* flags = (unsigned*)(ws + OFF_FLG);

  const int tid = threadIdx.x;
  const int jb = blockIdx.x;
  const int bg = jb & 3;          // batch group (16 batches)
  const int hs = jb >> 2;         // h-slice index (16 h columns)
  const int h0 = hs * 16;
  const int lane = tid & 63;
  const int wave = tid >> 6;
  const int ln15 = lane & 15;
  const int kg = lane >> 4;
  const int h = h0 + ln15;
  const int Bl = 4 * wave + kg;   // this lane's epilogue batch (wave owns [4w,4w+4))

  // one-time LDS staging of U and W slices for this h-slice
  for (int e = tid * 8; e < 3 * 16 * 1024; e += NTHR * 8) {
    int row = e >> 10, k = e & 1023;
    int g = row >> 4, hi = row & 15;
    uint4 v = *(const uint4*)(ubf + ((u64)(g * H_ + h0 + hi) * H_ + k));
    *(uint4*)((char*)u_lds + SWZ(row, (k << 1), 11)) = v;
  }
  for (int e = tid * 8; e < 3 * 16 * 512; e += NTHR * 8) {
    int row = e >> 9, k = e & 511;
    int g = row >> 4, hi = row & 15;
    uint4 v = *(const uint4*)(wbf + ((u64)(g * H_ + h0 + hi) * I_ + k));
    *(uint4*)((char*)w_lds + SWZ(row, (k << 1), 10)) = v;
  }
  const float bzv = bz[h];
  const float brv = br[h];
  const float bsv = bs[h];
  float sreg = s0[(u64)(bg * 16 + Bl) * H_ + h];   // 1 master state value/lane
  float mv = mask[(u64)(bg * 16 + Bl) * T_];       // mask for t=0
  __syncthreads();

  // ---- HOIST: all loop-invariant B-fragments into registers (36 x 16B) ----
  // Removes every per-step ds_read from the exchange critical path.
  s16x8 fb0[8], fb1[8], fb2[8];   // U B-frags (gate z, r, s) for this wave's kc range
  #pragma unroll
  for (int q = 0; q < 8; ++q) {
    const int cb = (wave * 8 + q) * 64 + kg * 16;
    fb0[q] = *(const s16x8*)((const char*)u_lds + SWZ(ln15, cb, 11));
    fb1[q] = *(const s16x8*)((const char*)u_lds + SWZ(16 + ln15, cb, 11));
    fb2[q] = *(const s16x8*)((const char*)u_lds + SWZ(32 + ln15, cb, 11));
  }
  s16x8 fw0[4], fw1[4], fw2[4];   // W B-frags for the x-projection
  #pragma unroll
  for (int i = 0; i < 4; ++i) {
    const int cb = (wave * 4 + i) * 64 + kg * 16;
    fw0[i] = *(const s16x8*)((const char*)w_lds + SWZ(ln15, cb, 10));
    fw1[i] = *(const s16x8*)((const char*)w_lds + SWZ(16 + ln15, cb, 10));
    fw2[i] = *(const s16x8*)((const char*)w_lds + SWZ(32 + ln15, cb, 10));
  }

  // consumer load bases (wave's kc range = wave*8 .. +8)
  const char* sbase = fsb + (((u64)bg * 32 + wave * 8) * 64 + lane) * 16;
  const char* rbase = frb + (((u64)bg * 32 + wave * 8) * 64 + lane) * 16;
  // producer chunk dst (active lanes l<8 per wave): batch 4w+(l&3), h-half l>>2
  const int lp = (4 * wave + (lane & 3)) + 16 * ((hs & 1) * 2 + ((lane >> 2) & 1));
  char* sdst = fsb + (((u64)bg * 32 + (hs >> 1)) * 64 + lp) * 16;
  char* rdst = frb + (((u64)bg * 32 + (hs >> 1)) * 64 + lp) * 16;
  unsigned* blockflag = flags + (u64)(bg * NMEM + hs) * 32;

  // x A-frags + x-projection partials for step 0 (off the exchange path)
  s16x8 xf[4];
  #pragma unroll
  for (int i = 0; i < 4; ++i) {
    const float* xp = x + ((u64)(bg * 16 + ln15) * T_) * I_ + (wave * 4 + i) * 32 + kg * 8;
    xf[i] = pack8(*(const float4*)xp, *(const float4*)(xp + 4));
  }
  f32x4 axz = {0.f,0.f,0.f,0.f}, axr = {0.f,0.f,0.f,0.f}, axs = {0.f,0.f,0.f,0.f};
  #pragma unroll
  for (int i = 0; i < 4; ++i) {
    axz = __builtin_amdgcn_mfma_f32_16x16x32_bf16(xf[i], fw0[i], axz, 0, 0, 0);
    axr = __builtin_amdgcn_mfma_f32_16x16x32_bf16(xf[i], fw1[i], axr, 0, 0, 0);
    axs = __builtin_amdgcn_mfma_f32_16x16x32_bf16(xf[i], fw2[i], axs, 0, 0, 0);
  }
  unsigned bidx = 0;
  float zval = 0.f;

  for (int t = 0; t < T_; ++t) {
    // ---------------- phase 1: z, r ----------------
    s16x8 aS[8];
    #pragma unroll
    for (int q = 0; q < 8; ++q) ld16_sc1(&aS[q], sbase + q * 1024);
    __builtin_amdgcn_sched_barrier(0);
    asm volatile("s_waitcnt vmcnt(0)" ::: "memory");
    __builtin_amdgcn_sched_barrier(0);
    f32x4 accz = axz, accr = axr;
    #pragma unroll
    for (int q = 0; q < 8; ++q) {
      accz = __builtin_amdgcn_mfma_f32_16x16x32_bf16(aS[q], fb0[q], accz, 0, 0, 0);
      accr = __builtin_amdgcn_mfma_f32_16x16x32_bf16(aS[q], fb1[q], accr, 0, 0, 0);
    }
    red1[wave][0][lane] = accz;
    red1[wave][1][lane] = accr;
    __syncthreads();
    ++bidx;
    {  // distributed epilogue: lane -> (batch Bl, col h)
      float az = 0.f, ar = 0.f;
      #pragma unroll
      for (int w2 = 0; w2 < 4; ++w2) {
        const float* pz = (const float*)&red1[w2][0][wave * 16 + ln15];
        const float* pr = (const float*)&red1[w2][1][wave * 16 + ln15];
        az += pz[kg];
        ar += pr[kg];
      }
      float z = 1.f / (1.f + __expf(-(az + bzv)));
      float r = 1.f / (1.f + __expf(-(ar + brv)));
      zval = z;
      tbw[wave][kg][ln15] = f2bf(sreg * r);     // wave-private transpose tile
      if (lane < 8) {
        s16x8 v = *(const s16x8*)&tbw[wave][lane & 3][((lane >> 2) & 1) * 8];
        st16_sc1(rdst, v);
      }
      asm volatile("s_waitcnt vmcnt(0)" ::: "memory");  // per-wave drain
    }
    __syncthreads();   // all waves' rs stores drained
    if (tid == 0)
      __hip_atomic_store(blockflag, bidx, __ATOMIC_RELAXED, __HIP_MEMORY_SCOPE_AGENT);
    bar_poll(flags, bg, bidx);

    // ---------------- phase 2: s_hat, state update ----------------
    s16x8 aR[8];
    #pragma unroll
    for (int q = 0; q < 8; ++q) ld16_sc1(&aR[q], rbase + q * 1024);
    __builtin_amdgcn_sched_barrier(0);
    asm volatile("s_waitcnt vmcnt(0)" ::: "memory");
    __builtin_amdgcn_sched_barrier(0);
    f32x4 accs = axs;
    #pragma unroll
    for (int q = 0; q < 8; ++q)
      accs = __builtin_amdgcn_mfma_f32_16x16x32_bf16(aR[q], fb2[q], accs, 0, 0, 0);
    red2[wave][lane] = accs;
    __syncthreads();
    ++bidx;
    float sf;
    {
      float as_ = 0.f;
      #pragma unroll
      for (int w2 = 0; w2 < 4; ++w2) {
        const float* ps = (const float*)&red2[w2][wave * 16 + ln15];
        as_ += ps[kg];
      }
      float shat = fmaxf(as_ + bsv, 0.f);
      float sn = (1.f - zval) * sreg + zval * shat;
      sf = sreg + mv * (sn - sreg);
      sreg = sf;
      tbw[wave][kg][ln15] = f2bf(sf);
      if (lane < 8) {
        s16x8 v = *(const s16x8*)&tbw[wave][lane & 3][((lane >> 2) & 1) * 8];
        st16_sc1(sdst, v);
      }
      asm volatile("s_waitcnt vmcnt(0)" ::: "memory");  // per-wave drain
    }
    __syncthreads();   // all waves' s stores drained
    if (tid == 0)
      __hip_atomic_store(blockflag, bidx, __ATOMIC_RELAXED, __HIP_MEMORY_SCOPE_AGENT);
    // out store after signal (64B-coalesced per batch row), off the drain path
    __builtin_nontemporal_store(sf, out + ((u64)(bg * 16 + Bl) * T_ + t) * H_ + h);
    // tail overlap: next step's x frags + 12 register-only x-MFMAs + mask
    if (t + 1 < T_) {
      #pragma unroll
      for (int i = 0; i < 4; ++i) {
        const float* xp = x + ((u64)(bg * 16 + ln15) * T_ + (t + 1)) * I_ + (wave * 4 + i) * 32 + kg * 8;
        xf[i] = pack8(*(const float4*)xp, *(const float4*)(xp + 4));
      }
      axz = f32x4{0.f,0.f,0.f,0.f}; axr = f32x4{0.f,0.f,0.f,0.f}; axs = f32x4{0.f,0.f,0.f,0.f};
      #pragma unroll
      for (int i = 0; i < 4; ++i) {
        axz = __builtin_amdgcn_mfma_f32_16x16x32_bf16(xf[i], fw0[i], axz, 0, 0, 0);
        axr = __builtin_amdgcn_mfma_f32_16x16x32_bf16(xf[i], fw1[i], axr, 0, 0, 0);
        axs = __builtin_amdgcn_mfma_f32_16x16x32_bf16(xf[i], fw2[i], axs, 0, 0, 0);
      }
      mv = mask[(u64)(bg * 16 + Bl) * T_ + (t + 1)];
    }
    bar_poll(flags, bg, bidx);
  }
}

extern "C" void kernel_launch(void* const* d_in, const int* in_sizes, int n_in,
                              void* d_out, int out_size, void* d_ws, size_t ws_size,
                              hipStream_t stream) {
  const float* x   = (const float*)d_in[0];
  const float* msk = (const float*)d_in[1];
  const float* s0  = (const float*)d_in[2];
  const float* Ws_ = (const float*)d_in[3];
  const float* Wr_ = (const float*)d_in[4];
  const float* Wz_ = (const float*)d_in[5];
  const float* Us_ = (const float*)d_in[6];
  const float* Ur_ = (const float*)d_in[7];
  const float* Uz_ = (const float*)d_in[8];
  const float* bs_ = (const float*)d_in[9];
  const float* br_ = (const float*)d_in[10];
  const float* bz_ = (const float*)d_in[11];
  float* out = (float*)d_out;
  char* ws = (char*)d_ws;

  (void)hipMemsetAsync(d_ws, 0, 32768, stream);  // per-block flags (128B spread)
  hipLaunchKernelGGL(prep_kernel, dim3(1024), dim3(256), 0, stream,
                     s0, Wz_, Wr_, Ws_, Uz_, Ur_, Us_, ws);
  hipLaunchKernelGGL(scan_kernel, dim3(NBLK), dim3(NTHR), 0, stream,
                     x, msk, bz_, br_, bs_, s0, ws, out);
}

// Round 15
// 2401.268 us; speedup vs baseline: 1.9019x; 1.0497x over previous
//
#include <hip/hip_runtime.h>

typedef unsigned short u16;
typedef unsigned long long u64;
typedef float f32x4 __attribute__((ext_vector_type(4)));
typedef short s16x8 __attribute__((ext_vector_type(8)));

#define B_ 64
#define T_ 512
#define I_ 512
#define H_ 1024
#define NBLK 256
#define NGRP 4      // batch groups (16 batches each), independent domains
#define NMEM 64     // blocks (h-slices) per group
#define NTHR 256

// workspace layout (bytes)
#define OFF_FLG 0                        // [4 bg][64 hs] x 128B = 32768
#define OFF_SBF 32768                    // s bf16 frags [4 bg][32 kc][64 lane]x16B = 131072
#define OFF_RS  (OFF_SBF + 131072)      // r*s bf16 frags, same layout = 131072
#define OFF_U   (OFF_RS + 131072)       // bf16 U row-major [3][1024][1024] = 6291456
#define OFF_W   (OFF_U + 6291456)       // bf16 W row-major [3][1024][512]  = 3145728

__device__ __forceinline__ u16 f2bf(float f) {
  unsigned u = __float_as_uint(f);
  return (u16)((u + 0x7FFFu + ((u >> 16) & 1u)) >> 16);
}

__device__ __forceinline__ s16x8 pack8(float4 a, float4 b) {
  s16x8 r;
  r[0] = (short)f2bf(a.x); r[1] = (short)f2bf(a.y);
  r[2] = (short)f2bf(a.z); r[3] = (short)f2bf(a.w);
  r[4] = (short)f2bf(b.x); r[5] = (short)f2bf(b.y);
  r[6] = (short)f2bf(b.z); r[7] = (short)f2bf(b.w);
  return r;
}

// 16B device-coherent (MALL-direct) load/store. Load returns before data
// arrives — caller MUST s_waitcnt + sched_barrier(0) before use.
__device__ __forceinline__ void ld16_sc1(s16x8* d, const char* p) {
  asm volatile("global_load_dwordx4 %0, %1, off sc0 sc1" : "=v"(*d) : "v"(p));
}
__device__ __forceinline__ void st16_sc1(char* p, s16x8 v) {
  asm volatile("global_store_dwordx4 %0, %1, off sc0 sc1" :: "v"(p), "v"(v) : "memory");
}

__global__ void prep_kernel(const float* __restrict__ s0,
                            const float* __restrict__ Wz, const float* __restrict__ Wr,
                            const float* __restrict__ Ws, const float* __restrict__ Uz,
                            const float* __restrict__ Ur, const float* __restrict__ Us,
                            char* __restrict__ ws) {
  u16* ubf = (u16*)(ws + OFF_U);
  u16* wbf = (u16*)(ws + OFF_W);
  int tid = blockIdx.x * blockDim.x + threadIdx.x;
  int stride = gridDim.x * blockDim.x;
  const int NU = H_ * H_;
  for (int i = tid; i < NU; i += stride) {
    ubf[i] = f2bf(Uz[i]);
    ubf[NU + i] = f2bf(Ur[i]);
    ubf[2 * NU + i] = f2bf(Us[i]);
  }
  const int NW = H_ * I_;
  for (int i = tid; i < NW; i += stride) {
    wbf[i] = f2bf(Wz[i]);
    wbf[NW + i] = f2bf(Wr[i]);
    wbf[2 * NW + i] = f2bf(Ws[i]);
  }
  // s0 -> frag-layout bf16: [bg][kc][lane]; b = bg*16 + (l&15), k = kc*32 + (l>>4)*8
  for (int f = tid; f < 4 * 32 * 64; f += stride) {
    int kc = (f >> 6) & 31, l = f & 63;
    int b = (f >> 11) * 16 + (l & 15);
    int k = kc * 32 + (l >> 4) * 8;
    const float* sp = s0 + (u64)b * H_ + k;
    ushort4 lo, hi;
    lo.x = f2bf(sp[0]); lo.y = f2bf(sp[1]); lo.z = f2bf(sp[2]); lo.w = f2bf(sp[3]);
    hi.x = f2bf(sp[4]); hi.y = f2bf(sp[5]); hi.z = f2bf(sp[6]); hi.w = f2bf(sp[7]);
    ushort4* dst = (ushort4*)(ws + OFF_SBF + (u64)f * 16);
    dst[0] = lo; dst[1] = hi;
  }
}

#define SWZ(row, byteInRow, rowShift) \
  (((((row) << (rowShift)) + (byteInRow))) ^ (((row) & 7) << 4))

__global__ __launch_bounds__(NTHR, 1) void scan_kernel(
    const float* __restrict__ x, const float* __restrict__ mask,
    const float* __restrict__ bz, const float* __restrict__ br,
    const float* __restrict__ bs, const float* __restrict__ s0,
    char* __restrict__ ws, float* __restrict__ out) {

  __shared__ u16 u_lds[3 * 16 * 1024];   // 96KB U slices (prologue staging only)
  __shared__ u16 w_lds[3 * 16 * 512];    // 48KB W slices (prologue staging only)
  __shared__ f32x4 red1[4][2][64];       // 8KB  P1 cross-wave reduction
  __shared__ f32x4 red2[4][64];          // 4KB  P2 cross-wave reduction
  __shared__ u16 tbw[4][4][16];          // 512B per-wave transpose tiles

  char* fsb = ws + OFF_SBF;
  char* frb = ws + OFF_RS;
  const u16* ubf = (const u16*)(ws + OFF_U);
  const u16* wbf = (const u16*)(ws + OFF_W);
  unsigned* flags = (unsigned*)(ws + OFF_FLG);

  const int tid = threadIdx.x;
  const int jb = blockIdx.x;
  const int bg = jb & 3;          // batch group (16 batches)
  const int hs = jb >> 2;         // h-slice index (16 h columns)
  const int h0 = hs * 16;
  const int lane = tid & 63;
  const int wave = tid >> 6;
  const int ln15 = lane & 15;
  const int kg = lane >> 4;
  const int h = h0 + ln15;
  const int Bl = 4 * wave + kg;   // this lane's epilogue batch (wave owns [4w,4w+4))

  // one-time LDS staging of U and W slices for this h-slice
  for (int e = tid * 8; e < 3 * 16 * 1024; e += NTHR * 8) {
    int row = e >> 10, k = e & 1023;
    int g = row >> 4, hi = row & 15;
    uint4 v = *(const uint4*)(ubf + ((u64)(g * H_ + h0 + hi) * H_ + k));
    *(uint4*)((char*)u_lds + SWZ(row, (k << 1), 11)) = v;
  }
  for (int e = tid * 8; e < 3 * 16 * 512; e += NTHR * 8) {
    int row = e >> 9, k = e & 511;
    int g = row >> 4, hi = row & 15;
    uint4 v = *(const uint4*)(wbf + ((u64)(g * H_ + h0 + hi) * I_ + k));
    *(uint4*)((char*)w_lds + SWZ(row, (k << 1), 10)) = v;
  }
  const float bzv = bz[h];
  const float brv = br[h];
  const float bsv = bs[h];
  float sreg = s0[(u64)(bg * 16 + Bl) * H_ + h];   // 1 master state value/lane
  float mv = mask[(u64)(bg * 16 + Bl) * T_];       // mask for t=0
  __syncthreads();

  // ---- HOIST: all loop-invariant B-fragments into registers (36 x 16B) ----
  s16x8 fb0[8], fb1[8], fb2[8];   // U B-frags (gate z, r, s) for this wave's kc range
  #pragma unroll
  for (int q = 0; q < 8; ++q) {
    const int cb = (wave * 8 + q) * 64 + kg * 16;
    fb0[q] = *(const s16x8*)((const char*)u_lds + SWZ(ln15, cb, 11));
    fb1[q] = *(const s16x8*)((const char*)u_lds + SWZ(16 + ln15, cb, 11));
    fb2[q] = *(const s16x8*)((const char*)u_lds + SWZ(32 + ln15, cb, 11));
  }
  s16x8 fw0[4], fw1[4], fw2[4];   // W B-frags for the x-projection
  #pragma unroll
  for (int i = 0; i < 4; ++i) {
    const int cb = (wave * 4 + i) * 64 + kg * 16;
    fw0[i] = *(const s16x8*)((const char*)w_lds + SWZ(ln15, cb, 10));
    fw1[i] = *(const s16x8*)((const char*)w_lds + SWZ(16 + ln15, cb, 10));
    fw2[i] = *(const s16x8*)((const char*)w_lds + SWZ(32 + ln15, cb, 10));
  }

  // consumer load bases (wave's kc range = wave*8 .. +8)
  const char* sbase = fsb + (((u64)bg * 32 + wave * 8) * 64 + lane) * 16;
  const char* rbase = frb + (((u64)bg * 32 + wave * 8) * 64 + lane) * 16;
  // producer chunk dst (active lanes l<8 per wave): batch 4w+(l&3), h-half l>>2
  const int lp = (4 * wave + (lane & 3)) + 16 * ((hs & 1) * 2 + ((lane >> 2) & 1));
  char* sdst = fsb + (((u64)bg * 32 + (hs >> 1)) * 64 + lp) * 16;
  char* rdst = frb + (((u64)bg * 32 + (hs >> 1)) * 64 + lp) * 16;
  unsigned* blockflag = flags + (u64)(bg * NMEM + hs) * 32;
  // per-wave dependency-exact poll: wave w needs ONLY producers hs in
  // [16w, 16w+16) (its k-range). Lane l<16 polls producer 16*wave+l.
  // Poll streams/block = 16 x 4 = 64 (same MALL pressure as the proven R10
  // shape; the R9/R11 regressions came from exceeding this).
  const unsigned* pollp = flags + (u64)(bg * NMEM + wave * 16 + ln15) * 32;

  // x A-frags + x-projection partials for step 0 (off the exchange path)
  s16x8 xf[4];
  #pragma unroll
  for (int i = 0; i < 4; ++i) {
    const float* xp = x + ((u64)(bg * 16 + ln15) * T_) * I_ + (wave * 4 + i) * 32 + kg * 8;
    xf[i] = pack8(*(const float4*)xp, *(const float4*)(xp + 4));
  }
  f32x4 axz = {0.f,0.f,0.f,0.f}, axr = {0.f,0.f,0.f,0.f}, axs = {0.f,0.f,0.f,0.f};
  #pragma unroll
  for (int i = 0; i < 4; ++i) {
    axz = __builtin_amdgcn_mfma_f32_16x16x32_bf16(xf[i], fw0[i], axz, 0, 0, 0);
    axr = __builtin_amdgcn_mfma_f32_16x16x32_bf16(xf[i], fw1[i], axr, 0, 0, 0);
    axs = __builtin_amdgcn_mfma_f32_16x16x32_bf16(xf[i], fw2[i], axs, 0, 0, 0);
  }
  unsigned bidx = 0;
  float zval = 0.f;

  for (int t = 0; t < T_; ++t) {
    // ---------------- phase 1: z, r ----------------
    s16x8 aS[8];
    #pragma unroll
    for (int q = 0; q < 8; ++q) ld16_sc1(&aS[q], sbase + q * 1024);
    __builtin_amdgcn_sched_barrier(0);
    asm volatile("s_waitcnt vmcnt(4)" ::: "memory");   // oldest 4 loads done
    __builtin_amdgcn_sched_barrier(0);
    f32x4 accz = axz, accr = axr;
    #pragma unroll
    for (int q = 0; q < 4; ++q) {
      accz = __builtin_amdgcn_mfma_f32_16x16x32_bf16(aS[q], fb0[q], accz, 0, 0, 0);
      accr = __builtin_amdgcn_mfma_f32_16x16x32_bf16(aS[q], fb1[q], accr, 0, 0, 0);
    }
    asm volatile("s_waitcnt vmcnt(0)" ::: "memory");
    __builtin_amdgcn_sched_barrier(0);
    #pragma unroll
    for (int q = 4; q < 8; ++q) {
      accz = __builtin_amdgcn_mfma_f32_16x16x32_bf16(aS[q], fb0[q], accz, 0, 0, 0);
      accr = __builtin_amdgcn_mfma_f32_16x16x32_bf16(aS[q], fb1[q], accr, 0, 0, 0);
    }
    red1[wave][0][lane] = accz;
    red1[wave][1][lane] = accr;
    __syncthreads();
    ++bidx;
    {  // distributed epilogue: lane -> (batch Bl, col h)
      float az = 0.f, ar = 0.f;
      #pragma unroll
      for (int w2 = 0; w2 < 4; ++w2) {
        const float* pz = (const float*)&red1[w2][0][wave * 16 + ln15];
        const float* pr = (const float*)&red1[w2][1][wave * 16 + ln15];
        az += pz[kg];
        ar += pr[kg];
      }
      float z = 1.f / (1.f + __expf(-(az + bzv)));
      float r = 1.f / (1.f + __expf(-(ar + brv)));
      zval = z;
      tbw[wave][kg][ln15] = f2bf(sreg * r);     // wave-private transpose tile
      if (lane < 8) {
        s16x8 v = *(const s16x8*)&tbw[wave][lane & 3][((lane >> 2) & 1) * 8];
        st16_sc1(rdst, v);
      }
      asm volatile("s_waitcnt vmcnt(0)" ::: "memory");  // per-wave drain
    }
    __syncthreads();   // all waves' rs stores drained
    if (tid == 0)
      __hip_atomic_store(blockflag, bidx, __ATOMIC_RELAXED, __HIP_MEMORY_SCOPE_AGENT);
    // per-wave poll of this wave's 16 producers; no block barrier needed
    if (lane < 16) {
      while (__hip_atomic_load(pollp, __ATOMIC_RELAXED, __HIP_MEMORY_SCOPE_AGENT) < bidx)
        __builtin_amdgcn_s_sleep(1);
    }

    // ---------------- phase 2: s_hat, state update ----------------
    s16x8 aR[8];
    #pragma unroll
    for (int q = 0; q < 8; ++q) ld16_sc1(&aR[q], rbase + q * 1024);
    __builtin_amdgcn_sched_barrier(0);
    asm volatile("s_waitcnt vmcnt(4)" ::: "memory");
    __builtin_amdgcn_sched_barrier(0);
    f32x4 accs = axs;
    #pragma unroll
    for (int q = 0; q < 4; ++q)
      accs = __builtin_amdgcn_mfma_f32_16x16x32_bf16(aR[q], fb2[q], accs, 0, 0, 0);
    asm volatile("s_waitcnt vmcnt(0)" ::: "memory");
    __builtin_amdgcn_sched_barrier(0);
    #pragma unroll
    for (int q = 4; q < 8; ++q)
      accs = __builtin_amdgcn_mfma_f32_16x16x32_bf16(aR[q], fb2[q], accs, 0, 0, 0);
    red2[wave][lane] = accs;
    __syncthreads();
    ++bidx;
    float sf;
    {
      float as_ = 0.f;
      #pragma unroll
      for (int w2 = 0; w2 < 4; ++w2) {
        const float* ps = (const float*)&red2[w2][wave * 16 + ln15];
        as_ += ps[kg];
      }
      float shat = fmaxf(as_ + bsv, 0.f);
      float sn = (1.f - zval) * sreg + zval * shat;
      sf = sreg + mv * (sn - sreg);
      sreg = sf;
      tbw[wave][kg][ln15] = f2bf(sf);
      if (lane < 8) {
        s16x8 v = *(const s16x8*)&tbw[wave][lane & 3][((lane >> 2) & 1) * 8];
        st16_sc1(sdst, v);
      }
      asm volatile("s_waitcnt vmcnt(0)" ::: "memory");  // per-wave drain
    }
    __syncthreads();   // all waves' s stores drained
    if (tid == 0)
      __hip_atomic_store(blockflag, bidx, __ATOMIC_RELAXED, __HIP_MEMORY_SCOPE_AGENT);
    // out store after signal (64B-coalesced per batch row), off the drain path
    __builtin_nontemporal_store(sf, out + ((u64)(bg * 16 + Bl) * T_ + t) * H_ + h);
    // tail overlap: next step's x frags + 12 register-only x-MFMAs + mask
    if (t + 1 < T_) {
      #pragma unroll
      for (int i = 0; i < 4; ++i) {
        const float* xp = x + ((u64)(bg * 16 + ln15) * T_ + (t + 1)) * I_ + (wave * 4 + i) * 32 + kg * 8;
        xf[i] = pack8(*(const float4*)xp, *(const float4*)(xp + 4));
      }
      axz = f32x4{0.f,0.f,0.f,0.f}; axr = f32x4{0.f,0.f,0.f,0.f}; axs = f32x4{0.f,0.f,0.f,0.f};
      #pragma unroll
      for (int i = 0; i < 4; ++i) {
        axz = __builtin_amdgcn_mfma_f32_16x16x32_bf16(xf[i], fw0[i], axz, 0, 0, 0);
        axr = __builtin_amdgcn_mfma_f32_16x16x32_bf16(xf[i], fw1[i], axr, 0, 0, 0);
        axs = __builtin_amdgcn_mfma_f32_16x16x32_bf16(xf[i], fw2[i], axs, 0, 0, 0);
      }
      mv = mask[(u64)(bg * 16 + Bl) * T_ + (t + 1)];
    }
    if (lane < 16) {
      while (__hip_atomic_load(pollp, __ATOMIC_RELAXED, __HIP_MEMORY_SCOPE_AGENT) < bidx)
        __builtin_amdgcn_s_sleep(1);
    }
  }
}

extern "C" void kernel_launch(void* const* d_in, const int* in_sizes, int n_in,
                              void* d_out, int out_size, void* d_ws, size_t ws_size,
                              hipStream_t stream) {
  const float* x   = (const float*)d_in[0];
  const float* msk = (const float*)d_in[1];
  const float* s0  = (const float*)d_in[2];
  const float* Ws_ = (const float*)d_in[3];
  const float* Wr_ = (const float*)d_in[4];
  const float* Wz_ = (const float*)d_in[5];
  const float* Us_ = (const float*)d_in[6];
  const float* Ur_ = (const float*)d_in[7];
  const float* Uz_ = (const float*)d_in[8];
  const float* bs_ = (const float*)d_in[9];
  const float* br_ = (const float*)d_in[10];
  const float* bz_ = (const float*)d_in[11];
  float* out = (float*)d_out;
  char* ws = (char*)d_ws;

  (void)hipMemsetAsync(d_ws, 0, 32768, stream);  // per-block flags (128B spread)
  hipLaunchKernelGGL(prep_kernel, dim3(1024), dim3(256), 0, stream,
                     s0, Wz_, Wr_, Ws_, Uz_, Ur_, Us_, ws);
  hipLaunchKernelGGL(scan_kernel, dim3(NBLK), dim3(NTHR), 0, stream,
                     x, msk, bz_, br_, bs_, s0, ws, out);
}

// Round 16
// 2172.659 us; speedup vs baseline: 2.1020x; 1.1052x over previous
//
#include <hip/hip_runtime.h>

typedef unsigned short u16;
typedef unsigned long long u64;
typedef float f32x4 __attribute__((ext_vector_type(4)));
typedef short s16x8 __attribute__((ext_vector_type(8)));

#define B_ 64
#define T_ 512
#define I_ 512
#define H_ 1024
#define NBLK 256
#define NGRP 4      // batch groups (16 batches each), independent domains
#define NMEM 64     // blocks (h-slices) per group
#define NTHR 256

// workspace layout (bytes)
#define OFF_FLG 0                        // [4 bg][64 hs] x 128B = 32768
#define OFF_SBF 32768                    // s bf16 frags [4 bg][32 kc][64 lane]x16B = 131072
#define OFF_RS  (OFF_SBF + 131072)      // r*s bf16 frags, same layout = 131072
#define OFF_U   (OFF_RS + 131072)       // bf16 U row-major [3][1024][1024] = 6291456
#define OFF_W   (OFF_U + 6291456)       // bf16 W row-major [3][1024][512]  = 3145728

__device__ __forceinline__ u16 f2bf(float f) {
  unsigned u = __float_as_uint(f);
  return (u16)((u + 0x7FFFu + ((u >> 16) & 1u)) >> 16);
}

__device__ __forceinline__ s16x8 pack8(float4 a, float4 b) {
  s16x8 r;
  r[0] = (short)f2bf(a.x); r[1] = (short)f2bf(a.y);
  r[2] = (short)f2bf(a.z); r[3] = (short)f2bf(a.w);
  r[4] = (short)f2bf(b.x); r[5] = (short)f2bf(b.y);
  r[6] = (short)f2bf(b.z); r[7] = (short)f2bf(b.w);
  return r;
}

// 16B device-coherent (MALL-direct) load/store. Load returns before data
// arrives — caller MUST s_waitcnt + sched_barrier(0) before use.
__device__ __forceinline__ void ld16_sc1(s16x8* d, const char* p) {
  asm volatile("global_load_dwordx4 %0, %1, off sc0 sc1" : "=v"(*d) : "v"(p));
}
__device__ __forceinline__ void st16_sc1(char* p, s16x8 v) {
  asm volatile("global_store_dwordx4 %0, %1, off sc0 sc1" :: "v"(p), "v"(v) : "memory");
}

__global__ void prep_kernel(const float* __restrict__ s0,
                            const float* __restrict__ Wz, const float* __restrict__ Wr,
                            const float* __restrict__ Ws, const float* __restrict__ Uz,
                            const float* __restrict__ Ur, const float* __restrict__ Us,
                            char* __restrict__ ws) {
  u16* ubf = (u16*)(ws + OFF_U);
  u16* wbf = (u16*)(ws + OFF_W);
  int tid = blockIdx.x * blockDim.x + threadIdx.x;
  int stride = gridDim.x * blockDim.x;
  const int NU = H_ * H_;
  for (int i = tid; i < NU; i += stride) {
    ubf[i] = f2bf(Uz[i]);
    ubf[NU + i] = f2bf(Ur[i]);
    ubf[2 * NU + i] = f2bf(Us[i]);
  }
  const int NW = H_ * I_;
  for (int i = tid; i < NW; i += stride) {
    wbf[i] = f2bf(Wz[i]);
    wbf[NW + i] = f2bf(Wr[i]);
    wbf[2 * NW + i] = f2bf(Ws[i]);
  }
  // s0 -> frag-layout bf16: [bg][kc][lane]; b = bg*16 + (l&15), k = kc*32 + (l>>4)*8
  for (int f = tid; f < 4 * 32 * 64; f += stride) {
    int kc = (f >> 6) & 31, l = f & 63;
    int b = (f >> 11) * 16 + (l & 15);
    int k = kc * 32 + (l >> 4) * 8;
    const float* sp = s0 + (u64)b * H_ + k;
    ushort4 lo, hi;
    lo.x = f2bf(sp[0]); lo.y = f2bf(sp[1]); lo.z = f2bf(sp[2]); lo.w = f2bf(sp[3]);
    hi.x = f2bf(sp[4]); hi.y = f2bf(sp[5]); hi.z = f2bf(sp[6]); hi.w = f2bf(sp[7]);
    ushort4* dst = (ushort4*)(ws + OFF_SBF + (u64)f * 16);
    dst[0] = lo; dst[1] = hi;
  }
}

#define SWZ(row, byteInRow, rowShift) \
  (((((row) << (rowShift)) + (byteInRow))) ^ (((row) & 7) << 4))

__global__ __launch_bounds__(NTHR, 1) void scan_kernel(
    const float* __restrict__ x, const float* __restrict__ mask,
    const float* __restrict__ bz, const float* __restrict__ br,
    const float* __restrict__ bs, const float* __restrict__ s0,
    char* __restrict__ ws, float* __restrict__ out) {

  __shared__ u16 u_lds[3 * 16 * 1024];   // 96KB U slices (prologue staging only)
  __shared__ u16 w_lds[3 * 16 * 512];    // 48KB W slices (prologue staging only)
  __shared__ f32x4 red1[4][2][64];       // 8KB  P1 cross-wave reduction
  __shared__ f32x4 red2[4][64];          // 4KB  P2 cross-wave reduction
  __shared__ u16 tbw[4][4][16];          // 512B per-wave transpose tiles

  char* fsb = ws + OFF_SBF;
  char* frb = ws + OFF_RS;
  const u16* ubf = (const u16*)(ws + OFF_U);
  const u16* wbf = (const u16*)(ws + OFF_W);
  unsigned* flags = (unsigned*)(ws + OFF_FLG);

  const int tid = threadIdx.x;
  const int jb = blockIdx.x;
  const int bg = jb & 3;          // batch group (16 batches)
  const int hs = jb >> 2;         // h-slice index (16 h columns)
  const int h0 = hs * 16;
  const int lane = tid & 63;
  const int wave = tid >> 6;
  const int ln15 = lane & 15;
  const int kg = lane >> 4;
  const int h = h0 + ln15;
  const int Bl = 4 * wave + kg;   // this lane's epilogue batch (wave owns [4w,4w+4))

  // one-time LDS staging of U and W slices for this h-slice
  for (int e = tid * 8; e < 3 * 16 * 1024; e += NTHR * 8) {
    int row = e >> 10, k = e & 1023;
    int g = row >> 4, hi = row & 15;
    uint4 v = *(const uint4*)(ubf + ((u64)(g * H_ + h0 + hi) * H_ + k));
    *(uint4*)((char*)u_lds + SWZ(row, (k << 1), 11)) = v;
  }
  for (int e = tid * 8; e < 3 * 16 * 512; e += NTHR * 8) {
    int row = e >> 9, k = e & 511;
    int g = row >> 4, hi = row & 15;
    uint4 v = *(const uint4*)(wbf + ((u64)(g * H_ + h0 + hi) * I_ + k));
    *(uint4*)((char*)w_lds + SWZ(row, (k << 1), 10)) = v;
  }
  const float bzv = bz[h];
  const float brv = br[h];
  const float bsv = bs[h];
  float sreg = s0[(u64)(bg * 16 + Bl) * H_ + h];   // 1 master state value/lane
  float mv = mask[(u64)(bg * 16 + Bl) * T_];       // mask for t=0
  __syncthreads();

  // ---- HOIST: all loop-invariant B-fragments into registers (36 x 16B) ----
  s16x8 fb0[8], fb1[8], fb2[8];   // U B-frags (gate z, r, s) for this wave's kc range
  #pragma unroll
  for (int q = 0; q < 8; ++q) {
    const int cb = (wave * 8 + q) * 64 + kg * 16;
    fb0[q] = *(const s16x8*)((const char*)u_lds + SWZ(ln15, cb, 11));
    fb1[q] = *(const s16x8*)((const char*)u_lds + SWZ(16 + ln15, cb, 11));
    fb2[q] = *(const s16x8*)((const char*)u_lds + SWZ(32 + ln15, cb, 11));
  }
  s16x8 fw0[4], fw1[4], fw2[4];   // W B-frags for the x-projection
  #pragma unroll
  for (int i = 0; i < 4; ++i) {
    const int cb = (wave * 4 + i) * 64 + kg * 16;
    fw0[i] = *(const s16x8*)((const char*)w_lds + SWZ(ln15, cb, 10));
    fw1[i] = *(const s16x8*)((const char*)w_lds + SWZ(16 + ln15, cb, 10));
    fw2[i] = *(const s16x8*)((const char*)w_lds + SWZ(32 + ln15, cb, 10));
  }

  // consumer load bases (wave's kc range = wave*8 .. +8)
  const char* sbase = fsb + (((u64)bg * 32 + wave * 8) * 64 + lane) * 16;
  const char* rbase = frb + (((u64)bg * 32 + wave * 8) * 64 + lane) * 16;
  // producer chunk dst (active lanes l<8 per wave): batch 4w+(l&3), h-half l>>2
  const int lp = (4 * wave + (lane & 3)) + 16 * ((hs & 1) * 2 + ((lane >> 2) & 1));
  char* sdst = fsb + (((u64)bg * 32 + (hs >> 1)) * 64 + lp) * 16;
  char* rdst = frb + (((u64)bg * 32 + (hs >> 1)) * 64 + lp) * 16;
  unsigned* blockflag = flags + (u64)(bg * NMEM + hs) * 32;
  // per-wave dependency-exact poll: wave w needs ONLY producers hs in
  // [16w, 16w+16). Lane l<16 polls producer 16*wave+l. 64 poll streams/block
  // (the proven-safe R10 pressure; R9/R11 regressions came from exceeding it).
  const unsigned* pollp = flags + (u64)(bg * NMEM + wave * 16 + ln15) * 32;

  // step-0 x A-frags + x-projection partials (off the exchange path)
  f32x4 axz = {0.f,0.f,0.f,0.f}, axr = {0.f,0.f,0.f,0.f}, axs = {0.f,0.f,0.f,0.f};
  {
    #pragma unroll
    for (int i = 0; i < 4; ++i) {
      const float* xp = x + ((u64)(bg * 16 + ln15) * T_) * I_ + (wave * 4 + i) * 32 + kg * 8;
      s16x8 xf_ = pack8(*(const float4*)xp, *(const float4*)(xp + 4));
      axz = __builtin_amdgcn_mfma_f32_16x16x32_bf16(xf_, fw0[i], axz, 0, 0, 0);
      axr = __builtin_amdgcn_mfma_f32_16x16x32_bf16(xf_, fw1[i], axr, 0, 0, 0);
      axs = __builtin_amdgcn_mfma_f32_16x16x32_bf16(xf_, fw2[i], axs, 0, 0, 0);
    }
  }
  float4 xraw[8];   // raw x for step t+1, issued in P1 tail (one phase early)
  float mvn = 0.f;
  unsigned bidx = 0;
  float zval = 0.f;

  for (int t = 0; t < T_; ++t) {
    // ---------------- phase 1: z, r ----------------
    s16x8 aS[8];
    #pragma unroll
    for (int q = 0; q < 8; ++q) ld16_sc1(&aS[q], sbase + q * 1024);
    __builtin_amdgcn_sched_barrier(0);
    asm volatile("s_waitcnt vmcnt(4)" ::: "memory");   // oldest 4 loads done
    __builtin_amdgcn_sched_barrier(0);
    f32x4 accz = axz, accr = axr;
    #pragma unroll
    for (int q = 0; q < 4; ++q) {
      accz = __builtin_amdgcn_mfma_f32_16x16x32_bf16(aS[q], fb0[q], accz, 0, 0, 0);
      accr = __builtin_amdgcn_mfma_f32_16x16x32_bf16(aS[q], fb1[q], accr, 0, 0, 0);
    }
    asm volatile("s_waitcnt vmcnt(0)" ::: "memory");
    __builtin_amdgcn_sched_barrier(0);
    #pragma unroll
    for (int q = 4; q < 8; ++q) {
      accz = __builtin_amdgcn_mfma_f32_16x16x32_bf16(aS[q], fb0[q], accz, 0, 0, 0);
      accr = __builtin_amdgcn_mfma_f32_16x16x32_bf16(aS[q], fb1[q], accr, 0, 0, 0);
    }
    red1[wave][0][lane] = accz;
    red1[wave][1][lane] = accr;
    __syncthreads();
    ++bidx;
    {  // distributed epilogue: lane -> (batch Bl, col h)
      float az = 0.f, ar = 0.f;
      #pragma unroll
      for (int w2 = 0; w2 < 4; ++w2) {
        const float* pz = (const float*)&red1[w2][0][wave * 16 + ln15];
        const float* pr = (const float*)&red1[w2][1][wave * 16 + ln15];
        az += pz[kg];
        ar += pr[kg];
      }
      float z = 1.f / (1.f + __expf(-(az + bzv)));
      float r = 1.f / (1.f + __expf(-(ar + brv)));
      zval = z;
      tbw[wave][kg][ln15] = f2bf(sreg * r);     // wave-private transpose tile
      if (lane < 8) {
        s16x8 v = *(const s16x8*)&tbw[wave][lane & 3][((lane >> 2) & 1) * 8];
        st16_sc1(rdst, v);
      }
      asm volatile("s_waitcnt vmcnt(0)" ::: "memory");  // per-wave drain (clean)
    }
    __syncthreads();   // all waves' rs stores drained
    if (tid == 0)
      __hip_atomic_store(blockflag, bidx, __ATOMIC_RELAXED, __HIP_MEMORY_SCOPE_AGENT);
    // P1 tail: ISSUE next step's raw x loads + mask now (one phase early) —
    // their latency hides under P1-poll + all of phase 2; P2's tail then has
    // no memory wait before its poll.
    if (t + 1 < T_) {
      #pragma unroll
      for (int i = 0; i < 4; ++i) {
        const float* xp = x + ((u64)(bg * 16 + ln15) * T_ + (t + 1)) * I_ + (wave * 4 + i) * 32 + kg * 8;
        xraw[2 * i]     = *(const float4*)xp;
        xraw[2 * i + 1] = *(const float4*)(xp + 4);
      }
      mvn = mask[(u64)(bg * 16 + Bl) * T_ + (t + 1)];
    }
    // per-wave poll of this wave's 16 producers
    if (lane < 16) {
      while (__hip_atomic_load(pollp, __ATOMIC_RELAXED, __HIP_MEMORY_SCOPE_AGENT) < bidx)
        __builtin_amdgcn_s_sleep(1);
    }

    // ---------------- phase 2: s_hat, state update ----------------
    s16x8 aR[8];
    #pragma unroll
    for (int q = 0; q < 8; ++q) ld16_sc1(&aR[q], rbase + q * 1024);
    __builtin_amdgcn_sched_barrier(0);
    asm volatile("s_waitcnt vmcnt(4)" ::: "memory");
    __builtin_amdgcn_sched_barrier(0);
    f32x4 accs = axs;
    #pragma unroll
    for (int q = 0; q < 4; ++q)
      accs = __builtin_amdgcn_mfma_f32_16x16x32_bf16(aR[q], fb2[q], accs, 0, 0, 0);
    asm volatile("s_waitcnt vmcnt(0)" ::: "memory");
    __builtin_amdgcn_sched_barrier(0);
    #pragma unroll
    for (int q = 4; q < 8; ++q)
      accs = __builtin_amdgcn_mfma_f32_16x16x32_bf16(aR[q], fb2[q], accs, 0, 0, 0);
    red2[wave][lane] = accs;
    __syncthreads();
    ++bidx;
    float sf;
    {
      float as_ = 0.f;
      #pragma unroll
      for (int w2 = 0; w2 < 4; ++w2) {
        const float* ps = (const float*)&red2[w2][wave * 16 + ln15];
        as_ += ps[kg];
      }
      float shat = fmaxf(as_ + bsv, 0.f);
      float sn = (1.f - zval) * sreg + zval * shat;
      sf = sreg + mv * (sn - sreg);
      sreg = sf;
      tbw[wave][kg][ln15] = f2bf(sf);
      if (lane < 8) {
        s16x8 v = *(const s16x8*)&tbw[wave][lane & 3][((lane >> 2) & 1) * 8];
        st16_sc1(sdst, v);
      }
      asm volatile("s_waitcnt vmcnt(0)" ::: "memory");  // per-wave drain
    }
    __syncthreads();   // all waves' s stores drained
    if (tid == 0)
      __hip_atomic_store(blockflag, bidx, __ATOMIC_RELAXED, __HIP_MEMORY_SCOPE_AGENT);
    // out store after signal (64B-coalesced per batch row), off the drain path
    __builtin_nontemporal_store(sf, out + ((u64)(bg * 16 + Bl) * T_ + t) * H_ + h);
    // P2 tail: x data already in registers (issued in P1 tail) — pure VALU/MFMA
    if (t + 1 < T_) {
      axz = f32x4{0.f,0.f,0.f,0.f}; axr = f32x4{0.f,0.f,0.f,0.f}; axs = f32x4{0.f,0.f,0.f,0.f};
      #pragma unroll
      for (int i = 0; i < 4; ++i) {
        s16x8 xf_ = pack8(xraw[2 * i], xraw[2 * i + 1]);
        axz = __builtin_amdgcn_mfma_f32_16x16x32_bf16(xf_, fw0[i], axz, 0, 0, 0);
        axr = __builtin_amdgcn_mfma_f32_16x16x32_bf16(xf_, fw1[i], axr, 0, 0, 0);
        axs = __builtin_amdgcn_mfma_f32_16x16x32_bf16(xf_, fw2[i], axs, 0, 0, 0);
      }
      mv = mvn;
    }
    if (lane < 16) {
      while (__hip_atomic_load(pollp, __ATOMIC_RELAXED, __HIP_MEMORY_SCOPE_AGENT) < bidx)
        __builtin_amdgcn_s_sleep(1);
    }
  }
}

extern "C" void kernel_launch(void* const* d_in, const int* in_sizes, int n_in,
                              void* d_out, int out_size, void* d_ws, size_t ws_size,
                              hipStream_t stream) {
  const float* x   = (const float*)d_in[0];
  const float* msk = (const float*)d_in[1];
  const float* s0  = (const float*)d_in[2];
  const float* Ws_ = (const float*)d_in[3];
  const float* Wr_ = (const float*)d_in[4];
  const float* Wz_ = (const float*)d_in[5];
  const float* Us_ = (const float*)d_in[6];
  const float* Ur_ = (const float*)d_in[7];
  const float* Uz_ = (const float*)d_in[8];
  const float* bs_ = (const float*)d_in[9];
  const float* br_ = (const float*)d_in[10];
  const float* bz_ = (const float*)d_in[11];
  float* out = (float*)d_out;
  char* ws = (char*)d_ws;

  (void)hipMemsetAsync(d_ws, 0, 32768, stream);  // per-block flags (128B spread)
  hipLaunchKernelGGL(prep_kernel, dim3(1024), dim3(256), 0, stream,
                     s0, Wz_, Wr_, Ws_, Uz_, Ur_, Us_, ws);
  hipLaunchKernelGGL(scan_kernel, dim3(NBLK), dim3(NTHR), 0, stream,
                     x, msk, bz_, br_, bs_, s0, ws, out);
}

// Round 17
// 2145.983 us; speedup vs baseline: 2.1281x; 1.0124x over previous
//
#include <hip/hip_runtime.h>

typedef unsigned short u16;
typedef unsigned long long u64;
typedef float f32x4 __attribute__((ext_vector_type(4)));
typedef short s16x8 __attribute__((ext_vector_type(8)));

#define B_ 64
#define T_ 512
#define I_ 512
#define H_ 1024
#define NBLK 256
#define NGRP 4      // batch groups (16 batches each), independent domains
#define NMEM 64     // blocks (h-slices) per group
#define NTHR 256

// workspace layout (bytes)
#define OFF_FLG 0                        // [4 bg][64 hs] x 128B = 32768
#define OFF_SBF 32768                    // s bf16 frags [4 bg][32 kc][64 lane]x16B = 131072
#define OFF_RS  (OFF_SBF + 131072)      // r*s bf16 frags, same layout = 131072
#define OFF_U   (OFF_RS + 131072)       // bf16 U row-major [3][1024][1024] = 6291456
#define OFF_W   (OFF_U + 6291456)       // bf16 W row-major [3][1024][512]  = 3145728

__device__ __forceinline__ u16 f2bf(float f) {
  unsigned u = __float_as_uint(f);
  return (u16)((u + 0x7FFFu + ((u >> 16) & 1u)) >> 16);
}

__device__ __forceinline__ s16x8 pack8(float4 a, float4 b) {
  s16x8 r;
  r[0] = (short)f2bf(a.x); r[1] = (short)f2bf(a.y);
  r[2] = (short)f2bf(a.z); r[3] = (short)f2bf(a.w);
  r[4] = (short)f2bf(b.x); r[5] = (short)f2bf(b.y);
  r[6] = (short)f2bf(b.z); r[7] = (short)f2bf(b.w);
  return r;
}

// 16B device-coherent (MALL-direct) load/store. Load returns before data
// arrives — caller MUST s_waitcnt + sched_barrier(0) before use.
__device__ __forceinline__ void ld16_sc1(s16x8* d, const char* p) {
  asm volatile("global_load_dwordx4 %0, %1, off sc0 sc1" : "=v"(*d) : "v"(p));
}
__device__ __forceinline__ void st16_sc1(char* p, s16x8 v) {
  asm volatile("global_store_dwordx4 %0, %1, off sc0 sc1" :: "v"(p), "v"(v) : "memory");
}

__global__ void prep_kernel(const float* __restrict__ s0,
                            const float* __restrict__ Wz, const float* __restrict__ Wr,
                            const float* __restrict__ Ws, const float* __restrict__ Uz,
                            const float* __restrict__ Ur, const float* __restrict__ Us,
                            char* __restrict__ ws) {
  u16* ubf = (u16*)(ws + OFF_U);
  u16* wbf = (u16*)(ws + OFF_W);
  int tid = blockIdx.x * blockDim.x + threadIdx.x;
  int stride = gridDim.x * blockDim.x;
  const int NU = H_ * H_;
  for (int i = tid; i < NU; i += stride) {
    ubf[i] = f2bf(Uz[i]);
    ubf[NU + i] = f2bf(Ur[i]);
    ubf[2 * NU + i] = f2bf(Us[i]);
  }
  const int NW = H_ * I_;
  for (int i = tid; i < NW; i += stride) {
    wbf[i] = f2bf(Wz[i]);
    wbf[NW + i] = f2bf(Wr[i]);
    wbf[2 * NW + i] = f2bf(Ws[i]);
  }
  // s0 -> frag-layout bf16: [bg][kc][lane]; b = bg*16 + (l&15), k = kc*32 + (l>>4)*8
  for (int f = tid; f < 4 * 32 * 64; f += stride) {
    int kc = (f >> 6) & 31, l = f & 63;
    int b = (f >> 11) * 16 + (l & 15);
    int k = kc * 32 + (l >> 4) * 8;
    const float* sp = s0 + (u64)b * H_ + k;
    ushort4 lo, hi;
    lo.x = f2bf(sp[0]); lo.y = f2bf(sp[1]); lo.z = f2bf(sp[2]); lo.w = f2bf(sp[3]);
    hi.x = f2bf(sp[4]); hi.y = f2bf(sp[5]); hi.z = f2bf(sp[6]); hi.w = f2bf(sp[7]);
    ushort4* dst = (ushort4*)(ws + OFF_SBF + (u64)f * 16);
    dst[0] = lo; dst[1] = hi;
  }
}

#define SWZ(row, byteInRow, rowShift) \
  (((((row) << (rowShift)) + (byteInRow))) ^ (((row) & 7) << 4))

__global__ __launch_bounds__(NTHR, 1) void scan_kernel(
    const float* __restrict__ x, const float* __restrict__ mask,
    const float* __restrict__ bz, const float* __restrict__ br,
    const float* __restrict__ bs, const float* __restrict__ s0,
    char* __restrict__ ws, float* __restrict__ out) {

  __shared__ u16 u_lds[3 * 16 * 1024];   // 96KB U slices (prologue staging only)
  __shared__ u16 w_lds[3 * 16 * 512];    // 48KB W slices (prologue staging only)
  __shared__ f32x4 red1[4][2][64];       // 8KB  P1 cross-wave reduction
  __shared__ f32x4 red2[4][64];          // 4KB  P2 cross-wave reduction
  __shared__ u16 tbw[4][4][16];          // 512B per-wave transpose tiles
  __shared__ unsigned wdone;             // monotonic wave-drain counter

  char* fsb = ws + OFF_SBF;
  char* frb = ws + OFF_RS;
  const u16* ubf = (const u16*)(ws + OFF_U);
  const u16* wbf = (const u16*)(ws + OFF_W);
  unsigned* flags = (unsigned*)(ws + OFF_FLG);

  const int tid = threadIdx.x;
  const int jb = blockIdx.x;
  const int bg = jb & 3;          // batch group (16 batches)
  const int hs = jb >> 2;         // h-slice index (16 h columns)
  const int h0 = hs * 16;
  const int lane = tid & 63;
  const int wave = tid >> 6;
  const int ln15 = lane & 15;
  const int kg = lane >> 4;
  const int h = h0 + ln15;
  const int Bl = 4 * wave + kg;   // this lane's epilogue batch (wave owns [4w,4w+4))

  // one-time LDS staging of U and W slices for this h-slice
  for (int e = tid * 8; e < 3 * 16 * 1024; e += NTHR * 8) {
    int row = e >> 10, k = e & 1023;
    int g = row >> 4, hi = row & 15;
    uint4 v = *(const uint4*)(ubf + ((u64)(g * H_ + h0 + hi) * H_ + k));
    *(uint4*)((char*)u_lds + SWZ(row, (k << 1), 11)) = v;
  }
  for (int e = tid * 8; e < 3 * 16 * 512; e += NTHR * 8) {
    int row = e >> 9, k = e & 511;
    int g = row >> 4, hi = row & 15;
    uint4 v = *(const uint4*)(wbf + ((u64)(g * H_ + h0 + hi) * I_ + k));
    *(uint4*)((char*)w_lds + SWZ(row, (k << 1), 10)) = v;
  }
  if (tid == 0) wdone = 0;
  const float bzv = bz[h];
  const float brv = br[h];
  const float bsv = bs[h];
  float sreg = s0[(u64)(bg * 16 + Bl) * H_ + h];   // 1 master state value/lane
  float mv = mask[(u64)(bg * 16 + Bl) * T_];       // mask for t=0
  __syncthreads();

  // ---- HOIST: all loop-invariant B-fragments into registers (36 x 16B) ----
  s16x8 fb0[8], fb1[8], fb2[8];   // U B-frags (gate z, r, s) for this wave's kc range
  #pragma unroll
  for (int q = 0; q < 8; ++q) {
    const int cb = (wave * 8 + q) * 64 + kg * 16;
    fb0[q] = *(const s16x8*)((const char*)u_lds + SWZ(ln15, cb, 11));
    fb1[q] = *(const s16x8*)((const char*)u_lds + SWZ(16 + ln15, cb, 11));
    fb2[q] = *(const s16x8*)((const char*)u_lds + SWZ(32 + ln15, cb, 11));
  }
  s16x8 fw0[4], fw1[4], fw2[4];   // W B-frags for the x-projection
  #pragma unroll
  for (int i = 0; i < 4; ++i) {
    const int cb = (wave * 4 + i) * 64 + kg * 16;
    fw0[i] = *(const s16x8*)((const char*)w_lds + SWZ(ln15, cb, 10));
    fw1[i] = *(const s16x8*)((const char*)w_lds + SWZ(16 + ln15, cb, 10));
    fw2[i] = *(const s16x8*)((const char*)w_lds + SWZ(32 + ln15, cb, 10));
  }

  // consumer load bases (wave's kc range = wave*8 .. +8)
  const char* sbase = fsb + (((u64)bg * 32 + wave * 8) * 64 + lane) * 16;
  const char* rbase = frb + (((u64)bg * 32 + wave * 8) * 64 + lane) * 16;
  // producer chunk dst (active lanes l<8 per wave): batch 4w+(l&3), h-half l>>2
  const int lp = (4 * wave + (lane & 3)) + 16 * ((hs & 1) * 2 + ((lane >> 2) & 1));
  char* sdst = fsb + (((u64)bg * 32 + (hs >> 1)) * 64 + lp) * 16;
  char* rdst = frb + (((u64)bg * 32 + (hs >> 1)) * 64 + lp) * 16;
  unsigned* blockflag = flags + (u64)(bg * NMEM + hs) * 32;
  // per-wave dependency-exact poll: wave w needs ONLY producers hs in
  // [16w, 16w+16). Lane l<16 polls producer 16*wave+l. 64 poll streams/block.
  const unsigned* pollp = flags + (u64)(bg * NMEM + wave * 16 + ln15) * 32;

  // step-0 x A-frags + x-projection partials (off the exchange path)
  f32x4 axz = {0.f,0.f,0.f,0.f}, axr = {0.f,0.f,0.f,0.f}, axs = {0.f,0.f,0.f,0.f};
  {
    #pragma unroll
    for (int i = 0; i < 4; ++i) {
      const float* xp = x + ((u64)(bg * 16 + ln15) * T_) * I_ + (wave * 4 + i) * 32 + kg * 8;
      s16x8 xf_ = pack8(*(const float4*)xp, *(const float4*)(xp + 4));
      axz = __builtin_amdgcn_mfma_f32_16x16x32_bf16(xf_, fw0[i], axz, 0, 0, 0);
      axr = __builtin_amdgcn_mfma_f32_16x16x32_bf16(xf_, fw1[i], axr, 0, 0, 0);
      axs = __builtin_amdgcn_mfma_f32_16x16x32_bf16(xf_, fw2[i], axs, 0, 0, 0);
    }
  }
  float4 xraw[8];   // raw x for step t+1, issued in P1 tail (one phase early)
  float mvn = 0.f;
  unsigned bidx = 0;
  float zval = 0.f;

  for (int t = 0; t < T_; ++t) {
    // ---------------- phase 1: z, r ----------------
    s16x8 aS[8];
    #pragma unroll
    for (int q = 0; q < 8; ++q) ld16_sc1(&aS[q], sbase + q * 1024);
    __builtin_amdgcn_sched_barrier(0);
    asm volatile("s_waitcnt vmcnt(4)" ::: "memory");   // oldest loads done
    __builtin_amdgcn_sched_barrier(0);
    f32x4 accz = axz, accr = axr;
    #pragma unroll
    for (int q = 0; q < 4; ++q) {
      accz = __builtin_amdgcn_mfma_f32_16x16x32_bf16(aS[q], fb0[q], accz, 0, 0, 0);
      accr = __builtin_amdgcn_mfma_f32_16x16x32_bf16(aS[q], fb1[q], accr, 0, 0, 0);
    }
    asm volatile("s_waitcnt vmcnt(0)" ::: "memory");
    __builtin_amdgcn_sched_barrier(0);
    #pragma unroll
    for (int q = 4; q < 8; ++q) {
      accz = __builtin_amdgcn_mfma_f32_16x16x32_bf16(aS[q], fb0[q], accz, 0, 0, 0);
      accr = __builtin_amdgcn_mfma_f32_16x16x32_bf16(aS[q], fb1[q], accr, 0, 0, 0);
    }
    red1[wave][0][lane] = accz;
    red1[wave][1][lane] = accr;
    __syncthreads();
    ++bidx;
    {  // distributed epilogue: lane -> (batch Bl, col h)
      float az = 0.f, ar = 0.f;
      #pragma unroll
      for (int w2 = 0; w2 < 4; ++w2) {
        const float* pz = (const float*)&red1[w2][0][wave * 16 + ln15];
        const float* pr = (const float*)&red1[w2][1][wave * 16 + ln15];
        az += pz[kg];
        ar += pr[kg];
      }
      float z = 1.f / (1.f + __expf(-(az + bzv)));
      float r = 1.f / (1.f + __expf(-(ar + brv)));
      zval = z;
      tbw[wave][kg][ln15] = f2bf(sreg * r);     // wave-private transpose tile
      if (lane < 8) {
        s16x8 v = *(const s16x8*)&tbw[wave][lane & 3][((lane >> 2) & 1) * 8];
        st16_sc1(rdst, v);
      }
      asm volatile("s_waitcnt vmcnt(0)" ::: "memory");  // per-wave drain
    }
    // waveless signal: each wave's lane0 increments the LDS drain counter
    // after ITS OWN drain; the 4th incrementer stores the flag. Non-last
    // waves proceed immediately (no block barrier).
    if (lane == 0) {
      unsigned old = __hip_atomic_fetch_add(&wdone, 1u, __ATOMIC_ACQ_REL,
                                            __HIP_MEMORY_SCOPE_WORKGROUP);
      if ((old & 3u) == 3u)
        __hip_atomic_store(blockflag, bidx, __ATOMIC_RELAXED, __HIP_MEMORY_SCOPE_AGENT);
    }
    // P1 tail: ISSUE next step's raw x loads + mask now (one phase early)
    if (t + 1 < T_) {
      #pragma unroll
      for (int i = 0; i < 4; ++i) {
        const float* xp = x + ((u64)(bg * 16 + ln15) * T_ + (t + 1)) * I_ + (wave * 4 + i) * 32 + kg * 8;
        xraw[2 * i]     = *(const float4*)xp;
        xraw[2 * i + 1] = *(const float4*)(xp + 4);
      }
      mvn = mask[(u64)(bg * 16 + Bl) * T_ + (t + 1)];
    }
    // per-wave busy poll of this wave's 16 producers (pacing = flag-load RTT)
    if (lane < 16) {
      while (__hip_atomic_load(pollp, __ATOMIC_RELAXED, __HIP_MEMORY_SCOPE_AGENT) < bidx) {}
    }

    // ---------------- phase 2: s_hat, state update ----------------
    s16x8 aR[8];
    #pragma unroll
    for (int q = 0; q < 8; ++q) ld16_sc1(&aR[q], rbase + q * 1024);
    __builtin_amdgcn_sched_barrier(0);
    asm volatile("s_waitcnt vmcnt(4)" ::: "memory");
    __builtin_amdgcn_sched_barrier(0);
    f32x4 accs = axs;
    #pragma unroll
    for (int q = 0; q < 4; ++q)
      accs = __builtin_amdgcn_mfma_f32_16x16x32_bf16(aR[q], fb2[q], accs, 0, 0, 0);
    asm volatile("s_waitcnt vmcnt(0)" ::: "memory");
    __builtin_amdgcn_sched_barrier(0);
    #pragma unroll
    for (int q = 4; q < 8; ++q)
      accs = __builtin_amdgcn_mfma_f32_16x16x32_bf16(aR[q], fb2[q], accs, 0, 0, 0);
    red2[wave][lane] = accs;
    __syncthreads();
    ++bidx;
    float sf;
    {
      float as_ = 0.f;
      #pragma unroll
      for (int w2 = 0; w2 < 4; ++w2) {
        const float* ps = (const float*)&red2[w2][wave * 16 + ln15];
        as_ += ps[kg];
      }
      float shat = fmaxf(as_ + bsv, 0.f);
      float sn = (1.f - zval) * sreg + zval * shat;
      sf = sreg + mv * (sn - sreg);
      sreg = sf;
      tbw[wave][kg][ln15] = f2bf(sf);
      if (lane < 8) {
        s16x8 v = *(const s16x8*)&tbw[wave][lane & 3][((lane >> 2) & 1) * 8];
        st16_sc1(sdst, v);
      }
      asm volatile("s_waitcnt vmcnt(0)" ::: "memory");  // per-wave drain
    }
    if (lane == 0) {
      unsigned old = __hip_atomic_fetch_add(&wdone, 1u, __ATOMIC_ACQ_REL,
                                            __HIP_MEMORY_SCOPE_WORKGROUP);
      if ((old & 3u) == 3u)
        __hip_atomic_store(blockflag, bidx, __ATOMIC_RELAXED, __HIP_MEMORY_SCOPE_AGENT);
    }
    // out store after signal (64B-coalesced per batch row), off the drain path
    __builtin_nontemporal_store(sf, out + ((u64)(bg * 16 + Bl) * T_ + t) * H_ + h);
    // P2 tail: x data already in registers (issued in P1 tail) — pure VALU/MFMA
    if (t + 1 < T_) {
      axz = f32x4{0.f,0.f,0.f,0.f}; axr = f32x4{0.f,0.f,0.f,0.f}; axs = f32x4{0.f,0.f,0.f,0.f};
      #pragma unroll
      for (int i = 0; i < 4; ++i) {
        s16x8 xf_ = pack8(xraw[2 * i], xraw[2 * i + 1]);
        axz = __builtin_amdgcn_mfma_f32_16x16x32_bf16(xf_, fw0[i], axz, 0, 0, 0);
        axr = __builtin_amdgcn_mfma_f32_16x16x32_bf16(xf_, fw1[i], axr, 0, 0, 0);
        axs = __builtin_amdgcn_mfma_f32_16x16x32_bf16(xf_, fw2[i], axs, 0, 0, 0);
      }
      mv = mvn;
    }
    if (lane < 16) {
      while (__hip_atomic_load(pollp, __ATOMIC_RELAXED, __HIP_MEMORY_SCOPE_AGENT) < bidx) {}
    }
  }
}

extern "C" void kernel_launch(void* const* d_in, const int* in_sizes, int n_in,
                              void* d_out, int out_size, void* d_ws, size_t ws_size,
                              hipStream_t stream) {
  const float* x   = (const float*)d_in[0];
  const float* msk = (const float*)d_in[1];
  const float* s0  = (const float*)d_in[2];
  const float* Ws_ = (const float*)d_in[3];
  const float* Wr_ = (const float*)d_in[4];
  const float* Wz_ = (const float*)d_in[5];
  const float* Us_ = (const float*)d_in[6];
  const float* Ur_ = (const float*)d_in[7];
  const float* Uz_ = (const float*)d_in[8];
  const float* bs_ = (const float*)d_in[9];
  const float* br_ = (const float*)d_in[10];
  const float* bz_ = (const float*)d_in[11];
  float* out = (float*)d_out;
  char* ws = (char*)d_ws;

  (void)hipMemsetAsync(d_ws, 0, 32768, stream);  // per-block flags (128B spread)
  hipLaunchKernelGGL(prep_kernel, dim3(1024), dim3(256), 0, stream,
                     s0, Wz_, Wr_, Ws_, Uz_, Ur_, Us_, ws);
  hipLaunchKernelGGL(scan_kernel, dim3(NBLK), dim3(NTHR), 0, stream,
                     x, msk, bz_, br_, bs_, s0, ws, out);
}